// Round 5
// baseline (871.520 us; speedup 1.0000x reference)
//
#include <hip/hip_runtime.h>
#include <math.h>

#define N_NODES 100000
#define N_EDGES 1600000
#define NB 1563          // ceil(N_NODES / 64) buckets, bucket = dst >> 6
#define CAP 2048         // bucket capacity (mean 1024 for uniform dst; 2x margin)

// ---------------- bucketed CSR build ----------------

__global__ void k_zero_i(int* __restrict__ p, int n) {
    int i = blockIdx.x * blockDim.x + threadIdx.x;
    if (i < n) p[i] = 0;
}

// Pass 1: append (dst_local, src) into per-bucket streams. Writes are
// sequential within each bucket -> cachelines fill before eviction.
__global__ void k_bucket(const int* __restrict__ src, const int* __restrict__ dst,
                         int* __restrict__ bcnt, unsigned* __restrict__ bentry) {
    int e = blockIdx.x * blockDim.x + threadIdx.x;
    if (e >= N_EDGES) return;
    int d = dst[e], s = src[e];
    int b = d >> 6;
    int pos = atomicAdd(&bcnt[b], 1);
    if (pos < CAP)
        bentry[(size_t)b * CAP + pos] = ((unsigned)(d & 63) << 17) | (unsigned)s;
}

// Exclusive scan of the 1563 bucket counts (single block, 2 chunks).
__global__ void k_bscan(const int* __restrict__ bcnt, int* __restrict__ bbase,
                        int* __restrict__ rowptr) {
    __shared__ int s[1024];
    __shared__ int carry;
    int t = threadIdx.x;
    if (t == 0) carry = 0;
    __syncthreads();
    for (int chunk = 0; chunk < 2; ++chunk) {
        int i = chunk * 1024 + t;
        int v = (i < NB) ? bcnt[i] : 0;
        s[t] = v;
        __syncthreads();
        for (int off = 1; off < 1024; off <<= 1) {
            int a = (t >= off) ? s[t - off] : 0;
            __syncthreads();
            s[t] += a;
            __syncthreads();
        }
        if (i < NB) bbase[i] = carry + s[t] - v;
        int total = carry + s[1023];
        __syncthreads();
        if (t == 0) carry = total;
        __syncthreads();
    }
    if (t == 0) rowptr[N_NODES] = N_EDGES;
}

// Pass 2: one block per bucket. LDS histogram -> degree/dinv/rowptr; LDS
// cursors -> colv scatter confined to the bucket's ~4KB contiguous window.
__global__ __launch_bounds__(256) void k_fill2(const int* __restrict__ bcnt,
                                               const int* __restrict__ bbase,
                                               const unsigned* __restrict__ bentry,
                                               int* __restrict__ rowptr,
                                               float* __restrict__ dinv,
                                               int* __restrict__ colv) {
    __shared__ unsigned ent[CAP];
    __shared__ int hist[64];
    __shared__ int cursor[64];
    int b = blockIdx.x;
    int t = threadIdx.x;
    int cnt = bcnt[b]; if (cnt > CAP) cnt = CAP;
    int base = bbase[b];
    if (t < 64) hist[t] = 0;
    __syncthreads();
    const unsigned* be = bentry + (size_t)b * CAP;
    for (int i = t; i < cnt; i += 256) {
        unsigned e = be[i];
        ent[i] = e;
        atomicAdd(&hist[e >> 17], 1);
    }
    __syncthreads();
    if (t < 64) {   // wave 0: scan the 64-bin histogram
        int v = hist[t];
        int incl = v;
#pragma unroll
        for (int off = 1; off < 64; off <<= 1) {
            int a = __shfl_up(incl, off);
            if (t >= off) incl += a;
        }
        int excl = incl - v;
        cursor[t] = excl;
        int node = (b << 6) + t;
        if (node < N_NODES) {
            rowptr[node] = base + excl;
            dinv[node] = rsqrtf((float)(v + 1));   // +1 self-loop
        }
    }
    __syncthreads();
    for (int i = t; i < cnt; i += 256) {
        unsigned e = ent[i];
        int pos = base + atomicAdd(&cursor[e >> 17], 1);
        colv[pos] = (int)(e & 0x1FFFF);
    }
}

// ---------------- tiled GEMM: h' = (in @ W) * dinv[node] ----------------
// Block 256 threads = 64-node x 64-col tile; X-tile + W-chunk in LDS (rows
// padded to 68 floats -> <=2-way bank aliasing, free). Each thread owns a
// 4x4 register tile.

template<int DIN>
__global__ __launch_bounds__(256) void k_gemm(const float* __restrict__ in,
                                              const float* __restrict__ W,
                                              const float* __restrict__ dinv,
                                              float* __restrict__ h) {
    __shared__ float sX[64 * 68];
    __shared__ float sW[64 * 68];
    int tid  = threadIdx.x;
    int lane = tid & 63, wave = tid >> 6;
    int node0 = blockIdx.x * 64;
    int r_base = wave * 16 + 4 * (lane >> 4);
    int c_base = 4 * (lane & 15);

    float acc[4][4] = {};

#pragma unroll
    for (int kc = 0; kc < DIN / 64; ++kc) {
#pragma unroll
        for (int i = 0; i < 4; ++i) {
            int idx = tid + i * 256;
            int row = idx >> 4;
            int j4  = (idx & 15) * 4;
            int nr  = node0 + row; if (nr >= N_NODES) nr = N_NODES - 1;
            *(float4*)(sX + row * 68 + j4) =
                *(const float4*)(in + (size_t)nr * DIN + kc * 64 + j4);
            *(float4*)(sW + row * 68 + j4) =
                *(const float4*)(W + (size_t)(kc * 64 + row) * 64 + j4);
        }
        __syncthreads();

#pragma unroll 16
        for (int k = 0; k < 64; ++k) {
            float4 wv = *(const float4*)(sW + k * 68 + c_base);
            float x0 = sX[(r_base + 0) * 68 + k];
            float x1 = sX[(r_base + 1) * 68 + k];
            float x2 = sX[(r_base + 2) * 68 + k];
            float x3 = sX[(r_base + 3) * 68 + k];
            acc[0][0] = fmaf(x0, wv.x, acc[0][0]); acc[0][1] = fmaf(x0, wv.y, acc[0][1]);
            acc[0][2] = fmaf(x0, wv.z, acc[0][2]); acc[0][3] = fmaf(x0, wv.w, acc[0][3]);
            acc[1][0] = fmaf(x1, wv.x, acc[1][0]); acc[1][1] = fmaf(x1, wv.y, acc[1][1]);
            acc[1][2] = fmaf(x1, wv.z, acc[1][2]); acc[1][3] = fmaf(x1, wv.w, acc[1][3]);
            acc[2][0] = fmaf(x2, wv.x, acc[2][0]); acc[2][1] = fmaf(x2, wv.y, acc[2][1]);
            acc[2][2] = fmaf(x2, wv.z, acc[2][2]); acc[2][3] = fmaf(x2, wv.w, acc[2][3]);
            acc[3][0] = fmaf(x3, wv.x, acc[3][0]); acc[3][1] = fmaf(x3, wv.y, acc[3][1]);
            acc[3][2] = fmaf(x3, wv.z, acc[3][2]); acc[3][3] = fmaf(x3, wv.w, acc[3][3]);
        }
        __syncthreads();
    }

#pragma unroll
    for (int i = 0; i < 4; ++i) {
        int r = node0 + r_base + i;
        if (r < N_NODES) {
            float dn = dinv[r];
            float4 o;
            o.x = acc[i][0] * dn; o.y = acc[i][1] * dn;
            o.z = acc[i][2] * dn; o.w = acc[i][3] * dn;
            *(float4*)(h + ((size_t)r << 6) + c_base) = o;
        }
    }
}

// ---------------- fused aggregate ----------------
// out[d] = relu( dinv[d] * (sum_{s in N(d)} h'[s] + h'[d]) + bias )
// (+ log-softmax if LAST). One wave per node; 4 quarter-waves x 16 lanes x
// float4 gather 4 edges per iteration, cross-quarter shfl reduce.

template<int LAST>
__global__ void k_aggregate(const int* __restrict__ rowptr, const int* __restrict__ colv,
                            const float* __restrict__ h, const float* __restrict__ dinv,
                            const float* __restrict__ bias, float* __restrict__ outp) {
    int node = blockIdx.x * (blockDim.x >> 6) + (threadIdx.x >> 6);
    if (node >= N_NODES) return;
    int lane = threadIdx.x & 63;
    int q  = lane >> 4;
    int ql = lane & 15;

    int beg = rowptr[node], end = rowptr[node + 1];

    float4 acc = make_float4(0.f, 0.f, 0.f, 0.f);
    for (int k = beg + q; k < end; k += 4) {
        int s = colv[k];
        float4 hv = *((const float4*)(h + ((size_t)s << 6)) + ql);
        acc.x += hv.x; acc.y += hv.y; acc.z += hv.z; acc.w += hv.w;
    }
#pragma unroll
    for (int off = 16; off <= 32; off <<= 1) {
        acc.x += __shfl_xor(acc.x, off);
        acc.y += __shfl_xor(acc.y, off);
        acc.z += __shfl_xor(acc.z, off);
        acc.w += __shfl_xor(acc.w, off);
    }
    float4 hv = *((const float4*)(h + ((size_t)node << 6)) + ql);
    float dn = dinv[node];
    float4 bv = ((const float4*)bias)[ql];
    float4 r;
    r.x = fmaxf(fmaf(acc.x + hv.x, dn, bv.x), 0.f);
    r.y = fmaxf(fmaf(acc.y + hv.y, dn, bv.y), 0.f);
    r.z = fmaxf(fmaf(acc.z + hv.z, dn, bv.z), 0.f);
    r.w = fmaxf(fmaf(acc.w + hv.w, dn, bv.w), 0.f);

    if (LAST) {
        float m = fmaxf(fmaxf(r.x, r.y), fmaxf(r.z, r.w));
#pragma unroll
        for (int off = 1; off <= 8; off <<= 1) m = fmaxf(m, __shfl_xor(m, off));
        float ssum = expf(r.x - m) + expf(r.y - m) + expf(r.z - m) + expf(r.w - m);
#pragma unroll
        for (int off = 1; off <= 8; off <<= 1) ssum += __shfl_xor(ssum, off);
        float lse = m + logf(ssum);
        r.x -= lse; r.y -= lse; r.z -= lse; r.w -= lse;
    }
    if (q == 0) *((float4*)(outp + ((size_t)node << 6)) + ql) = r;
}

// ---------------- launch ----------------

extern "C" void kernel_launch(void* const* d_in, const int* in_sizes, int n_in,
                              void* d_out, int out_size, void* d_ws, size_t ws_size,
                              hipStream_t stream) {
    const float* x = (const float*)d_in[0];
    const int* ei  = (const int*)d_in[1];   // harness delivers integers as int32
    const int* src = ei;
    const int* dst = ei + N_EDGES;

    const float* W[6];
    const float* b[6];
    for (int i = 0; i < 6; ++i) {
        W[i] = (const float*)d_in[2 + 2 * i];
        b[i] = (const float*)d_in[3 + 2 * i];
    }
    float* out = (float*)d_out;

    // workspace: rowptr [N+1] | dinv [N] | colv [E] | h [N*64]
    // bucket arrays (build-only) alias the h region (dead until first GEMM).
    char* p = (char*)d_ws;
    int*   rowptr = (int*)p;    p += (size_t)(N_NODES + 1) * 4;
    float* dinv   = (float*)p;  p += (size_t)N_NODES * 4;
    int*   colv   = (int*)p;    p += (size_t)N_EDGES * 4;
    float* h      = (float*)p;  // N_NODES*64 floats (25.6 MB)
    unsigned* bentry = (unsigned*)h;                        // 12.8 MB
    int*   bcnt   = (int*)(bentry + (size_t)NB * CAP);      // 6.3 KB
    int*   bbase  = bcnt + NB;

    const int nb_edge = (N_EDGES + 255) / 256;
    const int nb_wave = (N_NODES + 3) / 4;      // aggregate: 1 node/wave
    const int nb_tile = (N_NODES + 63) / 64;    // gemm: 64 nodes/block

    // CSR build (every call; deterministic work)
    k_zero_i<<<(NB + 255) / 256, 256, 0, stream>>>(bcnt, NB);
    k_bucket<<<nb_edge, 256, 0, stream>>>(src, dst, bcnt, bentry);
    k_bscan<<<1, 1024, 0, stream>>>(bcnt, bbase, rowptr);
    k_fill2<<<NB, 256, 0, stream>>>(bcnt, bbase, bentry, rowptr, dinv, colv);

    // 6 GCN layers; gemm(cur -> h), aggregate(h -> d_out)
    const float* cur = x;
    for (int l = 0; l < 6; ++l) {
        if (l == 0)
            k_gemm<128><<<nb_tile, 256, 0, stream>>>(cur, W[l], dinv, h);
        else
            k_gemm<64><<<nb_tile, 256, 0, stream>>>(cur, W[l], dinv, h);
        if (l == 5)
            k_aggregate<1><<<nb_wave, 256, 0, stream>>>(rowptr, colv, h, dinv, b[l], out);
        else
            k_aggregate<0><<<nb_wave, 256, 0, stream>>>(rowptr, colv, h, dinv, b[l], out);
        cur = out;
    }
}

// Round 6
// 691.391 us; speedup vs baseline: 1.2605x; 1.2605x over previous
//
#include <hip/hip_runtime.h>
#include <math.h>

#define N_NODES 100000
#define N_EDGES 1600000
#define NB 1563          // ceil(N_NODES / 64) buckets, bucket = dst >> 6
#define CAP 2048         // LDS staging per bucket in k_fill2 (mean 1024, sd ~32)
#define NBLK_S 64        // scatter/hist blocks
#define CHUNK ((N_EDGES + NBLK_S - 1) / NBLK_S)   // 25000 edges per block

// ---------------- counting-sort CSR build ----------------

// Pass 1: per-block histogram over buckets (LDS), write ghist[b][blk].
__global__ __launch_bounds__(256) void k_hist(const int* __restrict__ dst,
                                              int* __restrict__ ghist) {
    __shared__ int hist[NB];
    int blk = blockIdx.x, t = threadIdx.x;
    for (int i = t; i < NB; i += 256) hist[i] = 0;
    __syncthreads();
    int beg = blk * CHUNK, end = min(beg + CHUNK, N_EDGES);
    for (int e = beg + t; e < end; e += 256)
        atomicAdd(&hist[dst[e] >> 6], 1);
    __syncthreads();
    for (int i = t; i < NB; i += 256) ghist[i * NBLK_S + blk] = hist[i];
}

// Pass 2: exclusive scan of the 64 block-counts within each bucket (1 wave).
__global__ void k_scanb(int* __restrict__ ghist, int* __restrict__ btot) {
    int b = blockIdx.x, t = threadIdx.x;
    int v = ghist[b * NBLK_S + t];
    int incl = v;
#pragma unroll
    for (int off = 1; off < 64; off <<= 1) {
        int a = __shfl_up(incl, off);
        if (t >= off) incl += a;
    }
    ghist[b * NBLK_S + t] = incl - v;
    if (t == 63) btot[b] = incl;
}

// Pass 3: exclusive scan of the 1563 bucket totals (single block, 2 chunks).
__global__ void k_scant(const int* __restrict__ btot, int* __restrict__ bbase,
                        int* __restrict__ rowptr) {
    __shared__ int s[1024];
    __shared__ int carry;
    int t = threadIdx.x;
    if (t == 0) carry = 0;
    __syncthreads();
    for (int chunk = 0; chunk < 2; ++chunk) {
        int i = chunk * 1024 + t;
        int v = (i < NB) ? btot[i] : 0;
        s[t] = v;
        __syncthreads();
        for (int off = 1; off < 1024; off <<= 1) {
            int a = (t >= off) ? s[t - off] : 0;
            __syncthreads();
            s[t] += a;
            __syncthreads();
        }
        if (i < NB) bbase[i] = carry + s[t] - v;
        int total = carry + s[1023];
        __syncthreads();
        if (t == 0) carry = total;
        __syncthreads();
    }
    if (t == 0) rowptr[N_NODES] = N_EDGES;
}

// Pass 4: scatter into bucket-sorted bentry. Each (block,bucket) region is
// exclusively owned by one block -> write lines fill from a single CU.
__global__ __launch_bounds__(256) void k_scatter(const int* __restrict__ src,
                                                 const int* __restrict__ dst,
                                                 const int* __restrict__ ghist,
                                                 const int* __restrict__ bbase,
                                                 unsigned* __restrict__ bentry) {
    __shared__ int cursor[NB];
    int blk = blockIdx.x, t = threadIdx.x;
    for (int i = t; i < NB; i += 256)
        cursor[i] = bbase[i] + ghist[i * NBLK_S + blk];
    __syncthreads();
    int beg = blk * CHUNK, end = min(beg + CHUNK, N_EDGES);
    for (int e = beg + t; e < end; e += 256) {
        int d = dst[e], s = src[e];
        int pos = atomicAdd(&cursor[d >> 6], 1);
        bentry[pos] = ((unsigned)(d & 63) << 17) | (unsigned)s;
    }
}

// Pass 5: one block per bucket; LDS histogram -> rowptr/dinv, LDS cursors ->
// colv scatter confined to the bucket's contiguous window.
__global__ __launch_bounds__(256) void k_fill2(const int* __restrict__ btot,
                                               const int* __restrict__ bbase,
                                               const unsigned* __restrict__ bentry,
                                               int* __restrict__ rowptr,
                                               float* __restrict__ dinv,
                                               int* __restrict__ colv) {
    __shared__ unsigned ent[CAP];
    __shared__ int hist[64];
    __shared__ int cursor[64];
    int b = blockIdx.x;
    int t = threadIdx.x;
    int cnt = btot[b]; if (cnt > CAP) cnt = CAP;
    int base = bbase[b];
    if (t < 64) hist[t] = 0;
    __syncthreads();
    const unsigned* be = bentry + base;
    for (int i = t; i < cnt; i += 256) {
        unsigned e = be[i];
        ent[i] = e;
        atomicAdd(&hist[e >> 17], 1);
    }
    __syncthreads();
    if (t < 64) {   // wave 0: scan the 64-bin histogram
        int v = hist[t];
        int incl = v;
#pragma unroll
        for (int off = 1; off < 64; off <<= 1) {
            int a = __shfl_up(incl, off);
            if (t >= off) incl += a;
        }
        int excl = incl - v;
        cursor[t] = excl;
        int node = (b << 6) + t;
        if (node < N_NODES) {
            rowptr[node] = base + excl;
            dinv[node] = rsqrtf((float)(v + 1));   // +1 self-loop
        }
    }
    __syncthreads();
    for (int i = t; i < cnt; i += 256) {
        unsigned e = ent[i];
        int pos = base + atomicAdd(&cursor[e >> 17], 1);
        colv[pos] = (int)(e & 0x1FFFF);
    }
}

// ---------------- tiled GEMM: h' = (in @ W) * dinv[node] ----------------
// Block 256 threads = 64-node x 64-col tile; X-tile + W-chunk in LDS (rows
// padded to 68 floats -> <=2-way bank aliasing, free). Each thread owns a
// 4x4 register tile.

template<int DIN>
__global__ __launch_bounds__(256) void k_gemm(const float* __restrict__ in,
                                              const float* __restrict__ W,
                                              const float* __restrict__ dinv,
                                              float* __restrict__ h) {
    __shared__ float sX[64 * 68];
    __shared__ float sW[64 * 68];
    int tid  = threadIdx.x;
    int lane = tid & 63, wave = tid >> 6;
    int node0 = blockIdx.x * 64;
    int r_base = wave * 16 + 4 * (lane >> 4);
    int c_base = 4 * (lane & 15);

    float acc[4][4] = {};

#pragma unroll
    for (int kc = 0; kc < DIN / 64; ++kc) {
#pragma unroll
        for (int i = 0; i < 4; ++i) {
            int idx = tid + i * 256;
            int row = idx >> 4;
            int j4  = (idx & 15) * 4;
            int nr  = node0 + row; if (nr >= N_NODES) nr = N_NODES - 1;
            *(float4*)(sX + row * 68 + j4) =
                *(const float4*)(in + (size_t)nr * DIN + kc * 64 + j4);
            *(float4*)(sW + row * 68 + j4) =
                *(const float4*)(W + (size_t)(kc * 64 + row) * 64 + j4);
        }
        __syncthreads();

#pragma unroll 16
        for (int k = 0; k < 64; ++k) {
            float4 wv = *(const float4*)(sW + k * 68 + c_base);
            float x0 = sX[(r_base + 0) * 68 + k];
            float x1 = sX[(r_base + 1) * 68 + k];
            float x2 = sX[(r_base + 2) * 68 + k];
            float x3 = sX[(r_base + 3) * 68 + k];
            acc[0][0] = fmaf(x0, wv.x, acc[0][0]); acc[0][1] = fmaf(x0, wv.y, acc[0][1]);
            acc[0][2] = fmaf(x0, wv.z, acc[0][2]); acc[0][3] = fmaf(x0, wv.w, acc[0][3]);
            acc[1][0] = fmaf(x1, wv.x, acc[1][0]); acc[1][1] = fmaf(x1, wv.y, acc[1][1]);
            acc[1][2] = fmaf(x1, wv.z, acc[1][2]); acc[1][3] = fmaf(x1, wv.w, acc[1][3]);
            acc[2][0] = fmaf(x2, wv.x, acc[2][0]); acc[2][1] = fmaf(x2, wv.y, acc[2][1]);
            acc[2][2] = fmaf(x2, wv.z, acc[2][2]); acc[2][3] = fmaf(x2, wv.w, acc[2][3]);
            acc[3][0] = fmaf(x3, wv.x, acc[3][0]); acc[3][1] = fmaf(x3, wv.y, acc[3][1]);
            acc[3][2] = fmaf(x3, wv.z, acc[3][2]); acc[3][3] = fmaf(x3, wv.w, acc[3][3]);
        }
        __syncthreads();
    }

#pragma unroll
    for (int i = 0; i < 4; ++i) {
        int r = node0 + r_base + i;
        if (r < N_NODES) {
            float dn = dinv[r];
            float4 o;
            o.x = acc[i][0] * dn; o.y = acc[i][1] * dn;
            o.z = acc[i][2] * dn; o.w = acc[i][3] * dn;
            *(float4*)(h + ((size_t)r << 6) + c_base) = o;
        }
    }
}

// ---------------- fused aggregate ----------------
// out[d] = relu( dinv[d] * (sum_{s in N(d)} h'[s] + h'[d]) + bias )
// (+ log-softmax if LAST). One wave per node; 4 quarter-waves x 16 lanes x
// float4 gather 4 edges per iteration, cross-quarter shfl reduce.

template<int LAST>
__global__ void k_aggregate(const int* __restrict__ rowptr, const int* __restrict__ colv,
                            const float* __restrict__ h, const float* __restrict__ dinv,
                            const float* __restrict__ bias, float* __restrict__ outp) {
    int node = blockIdx.x * (blockDim.x >> 6) + (threadIdx.x >> 6);
    if (node >= N_NODES) return;
    int lane = threadIdx.x & 63;
    int q  = lane >> 4;
    int ql = lane & 15;

    int beg = rowptr[node], end = rowptr[node + 1];

    float4 acc = make_float4(0.f, 0.f, 0.f, 0.f);
    for (int k = beg + q; k < end; k += 4) {
        int s = colv[k];
        float4 hv = *((const float4*)(h + ((size_t)s << 6)) + ql);
        acc.x += hv.x; acc.y += hv.y; acc.z += hv.z; acc.w += hv.w;
    }
#pragma unroll
    for (int off = 16; off <= 32; off <<= 1) {
        acc.x += __shfl_xor(acc.x, off);
        acc.y += __shfl_xor(acc.y, off);
        acc.z += __shfl_xor(acc.z, off);
        acc.w += __shfl_xor(acc.w, off);
    }
    float4 hv = *((const float4*)(h + ((size_t)node << 6)) + ql);
    float dn = dinv[node];
    float4 bv = ((const float4*)bias)[ql];
    float4 r;
    r.x = fmaxf(fmaf(acc.x + hv.x, dn, bv.x), 0.f);
    r.y = fmaxf(fmaf(acc.y + hv.y, dn, bv.y), 0.f);
    r.z = fmaxf(fmaf(acc.z + hv.z, dn, bv.z), 0.f);
    r.w = fmaxf(fmaf(acc.w + hv.w, dn, bv.w), 0.f);

    if (LAST) {
        float m = fmaxf(fmaxf(r.x, r.y), fmaxf(r.z, r.w));
#pragma unroll
        for (int off = 1; off <= 8; off <<= 1) m = fmaxf(m, __shfl_xor(m, off));
        float ssum = expf(r.x - m) + expf(r.y - m) + expf(r.z - m) + expf(r.w - m);
#pragma unroll
        for (int off = 1; off <= 8; off <<= 1) ssum += __shfl_xor(ssum, off);
        float lse = m + logf(ssum);
        r.x -= lse; r.y -= lse; r.z -= lse; r.w -= lse;
    }
    if (q == 0) *((float4*)(outp + ((size_t)node << 6)) + ql) = r;
}

// ---------------- launch ----------------

extern "C" void kernel_launch(void* const* d_in, const int* in_sizes, int n_in,
                              void* d_out, int out_size, void* d_ws, size_t ws_size,
                              hipStream_t stream) {
    const float* x = (const float*)d_in[0];
    const int* ei  = (const int*)d_in[1];   // harness delivers integers as int32
    const int* src = ei;
    const int* dst = ei + N_EDGES;

    const float* W[6];
    const float* b[6];
    for (int i = 0; i < 6; ++i) {
        W[i] = (const float*)d_in[2 + 2 * i];
        b[i] = (const float*)d_in[3 + 2 * i];
    }
    float* out = (float*)d_out;

    // workspace: rowptr [N+1] | dinv [N] | colv [E] | h [N*64]
    // build-only arrays alias the h region (dead until first GEMM).
    char* p = (char*)d_ws;
    int*   rowptr = (int*)p;    p += (size_t)(N_NODES + 1) * 4;
    float* dinv   = (float*)p;  p += (size_t)N_NODES * 4;
    int*   colv   = (int*)p;    p += (size_t)N_EDGES * 4;
    float* h      = (float*)p;  // N_NODES*64 floats (25.6 MB)
    unsigned* bentry = (unsigned*)h;                       // 6.4 MB
    int*   ghist = (int*)(bentry + (size_t)N_EDGES);       // NB*64 ints (400 KB)
    int*   btot  = ghist + (size_t)NB * NBLK_S;            // NB ints
    int*   bbase = btot + NB;                              // NB ints

    const int nb_wave = (N_NODES + 3) / 4;      // aggregate: 1 node/wave
    const int nb_tile = (N_NODES + 63) / 64;    // gemm: 64 nodes/block

    // CSR build: counting sort by bucket, then in-bucket refine.
    k_hist<<<NBLK_S, 256, 0, stream>>>(dst, ghist);
    k_scanb<<<NB, 64, 0, stream>>>(ghist, btot);
    k_scant<<<1, 1024, 0, stream>>>(btot, bbase, rowptr);
    k_scatter<<<NBLK_S, 256, 0, stream>>>(src, dst, ghist, bbase, bentry);
    k_fill2<<<NB, 256, 0, stream>>>(btot, bbase, bentry, rowptr, dinv, colv);

    // 6 GCN layers; gemm(cur -> h), aggregate(h -> d_out)
    const float* cur = x;
    for (int l = 0; l < 6; ++l) {
        if (l == 0)
            k_gemm<128><<<nb_tile, 256, 0, stream>>>(cur, W[l], dinv, h);
        else
            k_gemm<64><<<nb_tile, 256, 0, stream>>>(cur, W[l], dinv, h);
        if (l == 5)
            k_aggregate<1><<<nb_wave, 256, 0, stream>>>(rowptr, colv, h, dinv, b[l], out);
        else
            k_aggregate<0><<<nb_wave, 256, 0, stream>>>(rowptr, colv, h, dinv, b[l], out);
        cur = out;
    }
}

// Round 7
// 591.759 us; speedup vs baseline: 1.4728x; 1.1684x over previous
//
#include <hip/hip_runtime.h>
#include <hip/hip_fp16.h>
#include <math.h>

#define N_NODES 100000
#define N_EDGES 1600000
#define NB 1563          // ceil(N_NODES / 64) buckets, bucket = dst >> 6
#define CAP 2048         // LDS staging per bucket in k_fill2 (mean 1024, sd ~32)
#define NBLK_S 64        // scatter/hist blocks
#define CHUNK ((N_EDGES + NBLK_S - 1) / NBLK_S)   // 25000 edges per block

// ---------------- counting-sort CSR build ----------------

// Pass 1: per-block histogram over buckets (LDS), write ghist[b][blk].
__global__ __launch_bounds__(256) void k_hist(const int* __restrict__ dst,
                                              int* __restrict__ ghist) {
    __shared__ int hist[NB];
    int blk = blockIdx.x, t = threadIdx.x;
    for (int i = t; i < NB; i += 256) hist[i] = 0;
    __syncthreads();
    int beg = blk * CHUNK, end = min(beg + CHUNK, N_EDGES);
    for (int e = beg + t; e < end; e += 256)
        atomicAdd(&hist[dst[e] >> 6], 1);
    __syncthreads();
    for (int i = t; i < NB; i += 256) ghist[i * NBLK_S + blk] = hist[i];
}

// Pass 2: exclusive scan of the 64 block-counts within each bucket (1 wave).
__global__ void k_scanb(int* __restrict__ ghist, int* __restrict__ btot) {
    int b = blockIdx.x, t = threadIdx.x;
    int v = ghist[b * NBLK_S + t];
    int incl = v;
#pragma unroll
    for (int off = 1; off < 64; off <<= 1) {
        int a = __shfl_up(incl, off);
        if (t >= off) incl += a;
    }
    ghist[b * NBLK_S + t] = incl - v;
    if (t == 63) btot[b] = incl;
}

// Pass 3: exclusive scan of the 1563 bucket totals (single block, 2 chunks).
__global__ void k_scant(const int* __restrict__ btot, int* __restrict__ bbase,
                        int* __restrict__ rowptr) {
    __shared__ int s[1024];
    __shared__ int carry;
    int t = threadIdx.x;
    if (t == 0) carry = 0;
    __syncthreads();
    for (int chunk = 0; chunk < 2; ++chunk) {
        int i = chunk * 1024 + t;
        int v = (i < NB) ? btot[i] : 0;
        s[t] = v;
        __syncthreads();
        for (int off = 1; off < 1024; off <<= 1) {
            int a = (t >= off) ? s[t - off] : 0;
            __syncthreads();
            s[t] += a;
            __syncthreads();
        }
        if (i < NB) bbase[i] = carry + s[t] - v;
        int total = carry + s[1023];
        __syncthreads();
        if (t == 0) carry = total;
        __syncthreads();
    }
    if (t == 0) rowptr[N_NODES] = N_EDGES;
}

// Pass 4: scatter into bucket-sorted bentry. Each (block,bucket) region is
// exclusively owned by one block -> write lines fill from a single CU.
__global__ __launch_bounds__(256) void k_scatter(const int* __restrict__ src,
                                                 const int* __restrict__ dst,
                                                 const int* __restrict__ ghist,
                                                 const int* __restrict__ bbase,
                                                 unsigned* __restrict__ bentry) {
    __shared__ int cursor[NB];
    int blk = blockIdx.x, t = threadIdx.x;
    for (int i = t; i < NB; i += 256)
        cursor[i] = bbase[i] + ghist[i * NBLK_S + blk];
    __syncthreads();
    int beg = blk * CHUNK, end = min(beg + CHUNK, N_EDGES);
    for (int e = beg + t; e < end; e += 256) {
        int d = dst[e], s = src[e];
        int pos = atomicAdd(&cursor[d >> 6], 1);
        bentry[pos] = ((unsigned)(d & 63) << 17) | (unsigned)s;
    }
}

// Pass 5: one block per bucket; LDS histogram -> rowptr/dinv, LDS cursors ->
// colv scatter confined to the bucket's contiguous window.
__global__ __launch_bounds__(256) void k_fill2(const int* __restrict__ btot,
                                               const int* __restrict__ bbase,
                                               const unsigned* __restrict__ bentry,
                                               int* __restrict__ rowptr,
                                               float* __restrict__ dinv,
                                               int* __restrict__ colv) {
    __shared__ unsigned ent[CAP];
    __shared__ int hist[64];
    __shared__ int cursor[64];
    int b = blockIdx.x;
    int t = threadIdx.x;
    int cnt = btot[b]; if (cnt > CAP) cnt = CAP;
    int base = bbase[b];
    if (t < 64) hist[t] = 0;
    __syncthreads();
    const unsigned* be = bentry + base;
    for (int i = t; i < cnt; i += 256) {
        unsigned e = be[i];
        ent[i] = e;
        atomicAdd(&hist[e >> 17], 1);
    }
    __syncthreads();
    if (t < 64) {   // wave 0: scan the 64-bin histogram
        int v = hist[t];
        int incl = v;
#pragma unroll
        for (int off = 1; off < 64; off <<= 1) {
            int a = __shfl_up(incl, off);
            if (t >= off) incl += a;
        }
        int excl = incl - v;
        cursor[t] = excl;
        int node = (b << 6) + t;
        if (node < N_NODES) {
            rowptr[node] = base + excl;
            dinv[node] = rsqrtf((float)(v + 1));   // +1 self-loop
        }
    }
    __syncthreads();
    for (int i = t; i < cnt; i += 256) {
        unsigned e = ent[i];
        int pos = base + atomicAdd(&cursor[e >> 17], 1);
        colv[pos] = (int)(e & 0x1FFFF);
    }
}

// ---------------- tiled GEMM: h' = (in @ W) * dinv[node], fp16 out --------
// Block 256 threads = 64-node x 64-col tile; X-tile + W-chunk staged in LDS
// as fp32 (rows padded to 68 -> <=2-way bank aliasing). 4x4 register tile
// per thread. Input fp32 (layer 0) or fp16 (layers 1-5); output fp16.

template<int DIN, int HALF_IN>
__global__ __launch_bounds__(256) void k_gemm(const void* __restrict__ in,
                                              const float* __restrict__ W,
                                              const float* __restrict__ dinv,
                                              __half* __restrict__ h) {
    __shared__ float sX[64 * 68];
    __shared__ float sW[64 * 68];
    int tid  = threadIdx.x;
    int lane = tid & 63, wave = tid >> 6;
    int node0 = blockIdx.x * 64;
    int r_base = wave * 16 + 4 * (lane >> 4);
    int c_base = 4 * (lane & 15);

    float acc[4][4] = {};

#pragma unroll
    for (int kc = 0; kc < DIN / 64; ++kc) {
#pragma unroll
        for (int i = 0; i < 4; ++i) {
            int idx = tid + i * 256;
            int row = idx >> 4;
            int j4  = (idx & 15) * 4;
            int nr  = node0 + row; if (nr >= N_NODES) nr = N_NODES - 1;
            if (HALF_IN) {
                union { uint2 u; __half2 h2[2]; } cv;
                cv.u = *(const uint2*)((const __half*)in + (size_t)nr * DIN + kc * 64 + j4);
                float2 f0 = __half22float2(cv.h2[0]);
                float2 f1 = __half22float2(cv.h2[1]);
                sX[row * 68 + j4 + 0] = f0.x; sX[row * 68 + j4 + 1] = f0.y;
                sX[row * 68 + j4 + 2] = f1.x; sX[row * 68 + j4 + 3] = f1.y;
            } else {
                *(float4*)(sX + row * 68 + j4) =
                    *(const float4*)((const float*)in + (size_t)nr * DIN + kc * 64 + j4);
            }
            *(float4*)(sW + row * 68 + j4) =
                *(const float4*)(W + (size_t)(kc * 64 + row) * 64 + j4);
        }
        __syncthreads();

#pragma unroll 16
        for (int k = 0; k < 64; ++k) {
            float4 wv = *(const float4*)(sW + k * 68 + c_base);
            float x0 = sX[(r_base + 0) * 68 + k];
            float x1 = sX[(r_base + 1) * 68 + k];
            float x2 = sX[(r_base + 2) * 68 + k];
            float x3 = sX[(r_base + 3) * 68 + k];
            acc[0][0] = fmaf(x0, wv.x, acc[0][0]); acc[0][1] = fmaf(x0, wv.y, acc[0][1]);
            acc[0][2] = fmaf(x0, wv.z, acc[0][2]); acc[0][3] = fmaf(x0, wv.w, acc[0][3]);
            acc[1][0] = fmaf(x1, wv.x, acc[1][0]); acc[1][1] = fmaf(x1, wv.y, acc[1][1]);
            acc[1][2] = fmaf(x1, wv.z, acc[1][2]); acc[1][3] = fmaf(x1, wv.w, acc[1][3]);
            acc[2][0] = fmaf(x2, wv.x, acc[2][0]); acc[2][1] = fmaf(x2, wv.y, acc[2][1]);
            acc[2][2] = fmaf(x2, wv.z, acc[2][2]); acc[2][3] = fmaf(x2, wv.w, acc[2][3]);
            acc[3][0] = fmaf(x3, wv.x, acc[3][0]); acc[3][1] = fmaf(x3, wv.y, acc[3][1]);
            acc[3][2] = fmaf(x3, wv.z, acc[3][2]); acc[3][3] = fmaf(x3, wv.w, acc[3][3]);
        }
        __syncthreads();
    }

#pragma unroll
    for (int i = 0; i < 4; ++i) {
        int r = node0 + r_base + i;
        if (r < N_NODES) {
            float dn = dinv[r];
            union { uint2 u; __half2 h2[2]; } pk;
            pk.h2[0] = __floats2half2_rn(acc[i][0] * dn, acc[i][1] * dn);
            pk.h2[1] = __floats2half2_rn(acc[i][2] * dn, acc[i][3] * dn);
            *(uint2*)(h + ((size_t)r << 6) + c_base) = pk.u;
        }
    }
}

// ---------------- fused aggregate (fp16 gather, fp32 accumulate) ----------
// out[d] = relu( dinv[d] * (sum_{s in N(d)} h'[s] + h'[d]) + bias )
// Non-last: write fp16 act. Last: fp32 log-softmax to d_out.
// One wave per node; 4 quarter-waves x 16 lanes x uint2(4 halves) gather 4
// edges (128B rows) per iteration, cross-quarter shfl reduce.

template<int LAST>
__global__ void k_aggregate(const int* __restrict__ rowptr, const int* __restrict__ colv,
                            const __half* __restrict__ h, const float* __restrict__ dinv,
                            const float* __restrict__ bias,
                            __half* __restrict__ acta, float* __restrict__ outf) {
    int node = blockIdx.x * (blockDim.x >> 6) + (threadIdx.x >> 6);
    if (node >= N_NODES) return;
    int lane = threadIdx.x & 63;
    int q  = lane >> 4;
    int ql = lane & 15;

    int beg = rowptr[node], end = rowptr[node + 1];

    float4 acc = make_float4(0.f, 0.f, 0.f, 0.f);
    for (int k = beg + q; k < end; k += 4) {
        int s = colv[k];
        union { uint2 u; __half2 h2[2]; } gv;
        gv.u = *((const uint2*)(h + ((size_t)s << 6)) + ql);
        float2 a0 = __half22float2(gv.h2[0]);
        float2 a1 = __half22float2(gv.h2[1]);
        acc.x += a0.x; acc.y += a0.y; acc.z += a1.x; acc.w += a1.y;
    }
#pragma unroll
    for (int off = 16; off <= 32; off <<= 1) {
        acc.x += __shfl_xor(acc.x, off);
        acc.y += __shfl_xor(acc.y, off);
        acc.z += __shfl_xor(acc.z, off);
        acc.w += __shfl_xor(acc.w, off);
    }
    // self-loop + normalize + bias + relu (all quarters hold identical values)
    union { uint2 u; __half2 h2[2]; } sv;
    sv.u = *((const uint2*)(h + ((size_t)node << 6)) + ql);
    float2 s0 = __half22float2(sv.h2[0]);
    float2 s1 = __half22float2(sv.h2[1]);
    float dn = dinv[node];
    float4 bv = ((const float4*)bias)[ql];
    float4 r;
    r.x = fmaxf(fmaf(acc.x + s0.x, dn, bv.x), 0.f);
    r.y = fmaxf(fmaf(acc.y + s0.y, dn, bv.y), 0.f);
    r.z = fmaxf(fmaf(acc.z + s1.x, dn, bv.z), 0.f);
    r.w = fmaxf(fmaf(acc.w + s1.y, dn, bv.w), 0.f);

    if (LAST) {
        float m = fmaxf(fmaxf(r.x, r.y), fmaxf(r.z, r.w));
#pragma unroll
        for (int off = 1; off <= 8; off <<= 1) m = fmaxf(m, __shfl_xor(m, off));
        float ssum = expf(r.x - m) + expf(r.y - m) + expf(r.z - m) + expf(r.w - m);
#pragma unroll
        for (int off = 1; off <= 8; off <<= 1) ssum += __shfl_xor(ssum, off);
        float lse = m + logf(ssum);
        r.x -= lse; r.y -= lse; r.z -= lse; r.w -= lse;
        if (q == 0) *((float4*)(outf + ((size_t)node << 6)) + ql) = r;
    } else {
        if (q == 0) {
            union { uint2 u; __half2 h2[2]; } pk;
            pk.h2[0] = __floats2half2_rn(r.x, r.y);
            pk.h2[1] = __floats2half2_rn(r.z, r.w);
            *((uint2*)(acta + ((size_t)node << 6)) + ql) = pk.u;
        }
    }
}

// ---------------- launch ----------------

extern "C" void kernel_launch(void* const* d_in, const int* in_sizes, int n_in,
                              void* d_out, int out_size, void* d_ws, size_t ws_size,
                              hipStream_t stream) {
    const float* x = (const float*)d_in[0];
    const int* ei  = (const int*)d_in[1];   // harness delivers integers as int32
    const int* src = ei;
    const int* dst = ei + N_EDGES;

    const float* W[6];
    const float* b[6];
    for (int i = 0; i < 6; ++i) {
        W[i] = (const float*)d_in[2 + 2 * i];
        b[i] = (const float*)d_in[3 + 2 * i];
    }
    float* out = (float*)d_out;

    // workspace: rowptr [N+1] | dinv [N] | colv [E] | h_fp16 [N*64] | act_fp16 [N*64]
    // build-only arrays alias the h region (dead until first GEMM).
    char* p = (char*)d_ws;
    int*    rowptr = (int*)p;    p += (size_t)(N_NODES + 1) * 4;
    float*  dinv   = (float*)p;  p += (size_t)N_NODES * 4;
    int*    colv   = (int*)p;    p += (size_t)N_EDGES * 4;
    __half* h      = (__half*)p; p += (size_t)N_NODES * 64 * 2;   // 12.8 MB
    __half* act    = (__half*)p;                                   // 12.8 MB
    unsigned* bentry = (unsigned*)h;                       // 6.4 MB (aliases h)
    int*    ghist = (int*)(bentry + (size_t)N_EDGES);      // NB*64 ints (400 KB)
    int*    btot  = ghist + (size_t)NB * NBLK_S;           // NB ints
    int*    bbase = btot + NB;                             // NB ints

    const int nb_wave = (N_NODES + 3) / 4;      // aggregate: 1 node/wave
    const int nb_tile = (N_NODES + 63) / 64;    // gemm: 64 nodes/block

    // CSR build: counting sort by bucket, then in-bucket refine.
    k_hist<<<NBLK_S, 256, 0, stream>>>(dst, ghist);
    k_scanb<<<NB, 64, 0, stream>>>(ghist, btot);
    k_scant<<<1, 1024, 0, stream>>>(btot, bbase, rowptr);
    k_scatter<<<NBLK_S, 256, 0, stream>>>(src, dst, ghist, bbase, bentry);
    k_fill2<<<NB, 256, 0, stream>>>(btot, bbase, bentry, rowptr, dinv, colv);

    // 6 GCN layers; gemm(cur -> h), aggregate(h -> act / d_out)
    for (int l = 0; l < 6; ++l) {
        if (l == 0)
            k_gemm<128, 0><<<nb_tile, 256, 0, stream>>>(x, W[l], dinv, h);
        else
            k_gemm<64, 1><<<nb_tile, 256, 0, stream>>>(act, W[l], dinv, h);
        if (l == 5)
            k_aggregate<1><<<nb_wave, 256, 0, stream>>>(rowptr, colv, h, dinv, b[l], act, out);
        else
            k_aggregate<0><<<nb_wave, 256, 0, stream>>>(rowptr, colv, h, dinv, b[l], act, out);
    }
}

// Round 8
// 525.339 us; speedup vs baseline: 1.6590x; 1.1264x over previous
//
#include <hip/hip_runtime.h>
#include <hip/hip_fp16.h>
#include <math.h>

#define N_NODES 100000
#define N_EDGES 1600000
#define NB 1563          // ceil(N_NODES / 64) buckets, bucket = dst >> 6
#define CAP 2048         // LDS staging per bucket in k_fill2 (mean 1024, sd ~32)
#define NBLK_S 64        // scatter/hist blocks
#define CHUNK ((N_EDGES + NBLK_S - 1) / NBLK_S)   // 25000 edges per block

// ---------------- counting-sort CSR build ----------------

// Pass 1: per-block histogram over buckets (LDS), write ghist[b][blk].
__global__ __launch_bounds__(256) void k_hist(const int* __restrict__ dst,
                                              int* __restrict__ ghist) {
    __shared__ int hist[NB];
    int blk = blockIdx.x, t = threadIdx.x;
    for (int i = t; i < NB; i += 256) hist[i] = 0;
    __syncthreads();
    int beg = blk * CHUNK, end = min(beg + CHUNK, N_EDGES);
    for (int e = beg + t; e < end; e += 256)
        atomicAdd(&hist[dst[e] >> 6], 1);
    __syncthreads();
    for (int i = t; i < NB; i += 256) ghist[i * NBLK_S + blk] = hist[i];
}

// Pass 2: exclusive scan of the 64 block-counts within each bucket (1 wave).
__global__ void k_scanb(int* __restrict__ ghist, int* __restrict__ btot) {
    int b = blockIdx.x, t = threadIdx.x;
    int v = ghist[b * NBLK_S + t];
    int incl = v;
#pragma unroll
    for (int off = 1; off < 64; off <<= 1) {
        int a = __shfl_up(incl, off);
        if (t >= off) incl += a;
    }
    ghist[b * NBLK_S + t] = incl - v;
    if (t == 63) btot[b] = incl;
}

// Pass 3: exclusive scan of the 1563 bucket totals (single block, 2 chunks).
__global__ void k_scant(const int* __restrict__ btot, int* __restrict__ bbase,
                        int* __restrict__ rowptr) {
    __shared__ int s[1024];
    __shared__ int carry;
    int t = threadIdx.x;
    if (t == 0) carry = 0;
    __syncthreads();
    for (int chunk = 0; chunk < 2; ++chunk) {
        int i = chunk * 1024 + t;
        int v = (i < NB) ? btot[i] : 0;
        s[t] = v;
        __syncthreads();
        for (int off = 1; off < 1024; off <<= 1) {
            int a = (t >= off) ? s[t - off] : 0;
            __syncthreads();
            s[t] += a;
            __syncthreads();
        }
        if (i < NB) bbase[i] = carry + s[t] - v;
        int total = carry + s[1023];
        __syncthreads();
        if (t == 0) carry = total;
        __syncthreads();
    }
    if (t == 0) rowptr[N_NODES] = N_EDGES;
}

// Pass 4: scatter into bucket-sorted bentry. Each (block,bucket) region is
// exclusively owned by one block -> write lines fill from a single CU.
__global__ __launch_bounds__(256) void k_scatter(const int* __restrict__ src,
                                                 const int* __restrict__ dst,
                                                 const int* __restrict__ ghist,
                                                 const int* __restrict__ bbase,
                                                 unsigned* __restrict__ bentry) {
    __shared__ int cursor[NB];
    int blk = blockIdx.x, t = threadIdx.x;
    for (int i = t; i < NB; i += 256)
        cursor[i] = bbase[i] + ghist[i * NBLK_S + blk];
    __syncthreads();
    int beg = blk * CHUNK, end = min(beg + CHUNK, N_EDGES);
    for (int e = beg + t; e < end; e += 256) {
        int d = dst[e], s = src[e];
        int pos = atomicAdd(&cursor[d >> 6], 1);
        bentry[pos] = ((unsigned)(d & 63) << 17) | (unsigned)s;
    }
}

// Pass 5: one block per bucket; LDS histogram -> rowptr/dinv, LDS cursors ->
// colv scatter confined to the bucket's contiguous window.
__global__ __launch_bounds__(256) void k_fill2(const int* __restrict__ btot,
                                               const int* __restrict__ bbase,
                                               const unsigned* __restrict__ bentry,
                                               int* __restrict__ rowptr,
                                               float* __restrict__ dinv,
                                               int* __restrict__ colv) {
    __shared__ unsigned ent[CAP];
    __shared__ int hist[64];
    __shared__ int cursor[64];
    int b = blockIdx.x;
    int t = threadIdx.x;
    int cnt = btot[b]; if (cnt > CAP) cnt = CAP;
    int base = bbase[b];
    if (t < 64) hist[t] = 0;
    __syncthreads();
    const unsigned* be = bentry + base;
    for (int i = t; i < cnt; i += 256) {
        unsigned e = be[i];
        ent[i] = e;
        atomicAdd(&hist[e >> 17], 1);
    }
    __syncthreads();
    if (t < 64) {   // wave 0: scan the 64-bin histogram
        int v = hist[t];
        int incl = v;
#pragma unroll
        for (int off = 1; off < 64; off <<= 1) {
            int a = __shfl_up(incl, off);
            if (t >= off) incl += a;
        }
        int excl = incl - v;
        cursor[t] = excl;
        int node = (b << 6) + t;
        if (node < N_NODES) {
            rowptr[node] = base + excl;
            dinv[node] = rsqrtf((float)(v + 1));   // +1 self-loop
        }
    }
    __syncthreads();
    for (int i = t; i < cnt; i += 256) {
        unsigned e = ent[i];
        int pos = base + atomicAdd(&cursor[e >> 17], 1);
        colv[pos] = (int)(e & 0x1FFFF);
    }
}

// ---------------- tiled GEMM: h' = (in @ W) * dinv[node], fp16 out --------
// Block 256 threads = 64-node x 64-col tile; X-tile + W-chunk staged in LDS
// as fp32 (rows padded to 68 -> <=2-way bank aliasing). 4x4 register tile
// per thread. Input fp32 (layer 0) or fp16 (layers 1-5); output fp16.

template<int DIN, int HALF_IN>
__global__ __launch_bounds__(256) void k_gemm(const void* __restrict__ in,
                                              const float* __restrict__ W,
                                              const float* __restrict__ dinv,
                                              __half* __restrict__ h) {
    __shared__ float sX[64 * 68];
    __shared__ float sW[64 * 68];
    int tid  = threadIdx.x;
    int lane = tid & 63, wave = tid >> 6;
    int node0 = blockIdx.x * 64;
    int r_base = wave * 16 + 4 * (lane >> 4);
    int c_base = 4 * (lane & 15);

    float acc[4][4] = {};

#pragma unroll
    for (int kc = 0; kc < DIN / 64; ++kc) {
#pragma unroll
        for (int i = 0; i < 4; ++i) {
            int idx = tid + i * 256;
            int row = idx >> 4;
            int j4  = (idx & 15) * 4;
            int nr  = node0 + row; if (nr >= N_NODES) nr = N_NODES - 1;
            if (HALF_IN) {
                union { uint2 u; __half2 h2[2]; } cv;
                cv.u = *(const uint2*)((const __half*)in + (size_t)nr * DIN + kc * 64 + j4);
                float2 f0 = __half22float2(cv.h2[0]);
                float2 f1 = __half22float2(cv.h2[1]);
                sX[row * 68 + j4 + 0] = f0.x; sX[row * 68 + j4 + 1] = f0.y;
                sX[row * 68 + j4 + 2] = f1.x; sX[row * 68 + j4 + 3] = f1.y;
            } else {
                *(float4*)(sX + row * 68 + j4) =
                    *(const float4*)((const float*)in + (size_t)nr * DIN + kc * 64 + j4);
            }
            *(float4*)(sW + row * 68 + j4) =
                *(const float4*)(W + (size_t)(kc * 64 + row) * 64 + j4);
        }
        __syncthreads();

#pragma unroll 16
        for (int k = 0; k < 64; ++k) {
            float4 wv = *(const float4*)(sW + k * 68 + c_base);
            float x0 = sX[(r_base + 0) * 68 + k];
            float x1 = sX[(r_base + 1) * 68 + k];
            float x2 = sX[(r_base + 2) * 68 + k];
            float x3 = sX[(r_base + 3) * 68 + k];
            acc[0][0] = fmaf(x0, wv.x, acc[0][0]); acc[0][1] = fmaf(x0, wv.y, acc[0][1]);
            acc[0][2] = fmaf(x0, wv.z, acc[0][2]); acc[0][3] = fmaf(x0, wv.w, acc[0][3]);
            acc[1][0] = fmaf(x1, wv.x, acc[1][0]); acc[1][1] = fmaf(x1, wv.y, acc[1][1]);
            acc[1][2] = fmaf(x1, wv.z, acc[1][2]); acc[1][3] = fmaf(x1, wv.w, acc[1][3]);
            acc[2][0] = fmaf(x2, wv.x, acc[2][0]); acc[2][1] = fmaf(x2, wv.y, acc[2][1]);
            acc[2][2] = fmaf(x2, wv.z, acc[2][2]); acc[2][3] = fmaf(x2, wv.w, acc[2][3]);
            acc[3][0] = fmaf(x3, wv.x, acc[3][0]); acc[3][1] = fmaf(x3, wv.y, acc[3][1]);
            acc[3][2] = fmaf(x3, wv.z, acc[3][2]); acc[3][3] = fmaf(x3, wv.w, acc[3][3]);
        }
        __syncthreads();
    }

#pragma unroll
    for (int i = 0; i < 4; ++i) {
        int r = node0 + r_base + i;
        if (r < N_NODES) {
            float dn = dinv[r];
            union { uint2 u; __half2 h2[2]; } pk;
            pk.h2[0] = __floats2half2_rn(acc[i][0] * dn, acc[i][1] * dn);
            pk.h2[1] = __floats2half2_rn(acc[i][2] * dn, acc[i][3] * dn);
            *(uint2*)(h + ((size_t)r << 6) + c_base) = pk.u;
        }
    }
}

// ---------------- fused aggregate (fp16 gather, fp32 accumulate) ----------
// out[d] = relu( dinv[d] * (sum_{s in N(d)} h'[s] + h'[d]) + bias )
// One wave per node; 8 octet-groups x 8 lanes x uint4 (8 halves) gather 8
// edges (128B rows) per iteration, unrolled x2 -> up to 16 edge-rows in
// flight per wave. 3-step cross-group shfl reduce.

template<int LAST>
__global__ void k_aggregate(const int* __restrict__ rowptr, const int* __restrict__ colv,
                            const __half* __restrict__ h, const float* __restrict__ dinv,
                            const float* __restrict__ bias,
                            __half* __restrict__ acta, float* __restrict__ outf) {
    int node = blockIdx.x * (blockDim.x >> 6) + (threadIdx.x >> 6);
    if (node >= N_NODES) return;
    int lane = threadIdx.x & 63;
    int g  = lane >> 3;    // edge slot 0..7
    int gl = lane & 7;     // 16B chunk within row (cols gl*8 .. gl*8+7)

    int beg = rowptr[node], end = rowptr[node + 1];

    float acc[8] = {};
    int k = beg + g;
    // unrolled by 2: two independent 16B gathers in flight per lane
    for (; k + 8 < end; k += 16) {
        int s0 = colv[k];
        int s1 = colv[k + 8];
        union { uint4 u; __half2 h2[4]; } a, b;
        a.u = *((const uint4*)(h + ((size_t)s0 << 6)) + gl);
        b.u = *((const uint4*)(h + ((size_t)s1 << 6)) + gl);
#pragma unroll
        for (int j = 0; j < 4; ++j) {
            float2 fa = __half22float2(a.h2[j]);
            float2 fb = __half22float2(b.h2[j]);
            acc[2 * j]     += fa.x + fb.x;
            acc[2 * j + 1] += fa.y + fb.y;
        }
    }
    if (k < end) {
        int s0 = colv[k];
        union { uint4 u; __half2 h2[4]; } a;
        a.u = *((const uint4*)(h + ((size_t)s0 << 6)) + gl);
#pragma unroll
        for (int j = 0; j < 4; ++j) {
            float2 fa = __half22float2(a.h2[j]);
            acc[2 * j]     += fa.x;
            acc[2 * j + 1] += fa.y;
        }
    }
    // reduce across the 8 octet groups (lane bits 3,4,5)
#pragma unroll
    for (int off = 8; off <= 32; off <<= 1) {
#pragma unroll
        for (int j = 0; j < 8; ++j) acc[j] += __shfl_xor(acc[j], off);
    }
    // self-loop + normalize + bias + relu (groups hold identical values)
    union { uint4 u; __half2 h2[4]; } sv;
    sv.u = *((const uint4*)(h + ((size_t)node << 6)) + gl);
    float dn = dinv[node];
    float4 bv0 = ((const float4*)bias)[gl * 2];
    float4 bv1 = ((const float4*)bias)[gl * 2 + 1];
    float r[8];
    {
        float2 s0 = __half22float2(sv.h2[0]);
        float2 s1 = __half22float2(sv.h2[1]);
        float2 s2 = __half22float2(sv.h2[2]);
        float2 s3 = __half22float2(sv.h2[3]);
        r[0] = fmaxf(fmaf(acc[0] + s0.x, dn, bv0.x), 0.f);
        r[1] = fmaxf(fmaf(acc[1] + s0.y, dn, bv0.y), 0.f);
        r[2] = fmaxf(fmaf(acc[2] + s1.x, dn, bv0.z), 0.f);
        r[3] = fmaxf(fmaf(acc[3] + s1.y, dn, bv0.w), 0.f);
        r[4] = fmaxf(fmaf(acc[4] + s2.x, dn, bv1.x), 0.f);
        r[5] = fmaxf(fmaf(acc[5] + s2.y, dn, bv1.y), 0.f);
        r[6] = fmaxf(fmaf(acc[6] + s3.x, dn, bv1.z), 0.f);
        r[7] = fmaxf(fmaf(acc[7] + s3.y, dn, bv1.w), 0.f);
    }

    if (LAST) {
        // log-softmax over 64 cols: reduce across gl groups (lane bits 0..2)
        float m = r[0];
#pragma unroll
        for (int j = 1; j < 8; ++j) m = fmaxf(m, r[j]);
#pragma unroll
        for (int off = 1; off <= 4; off <<= 1) m = fmaxf(m, __shfl_xor(m, off));
        float ssum = 0.f;
#pragma unroll
        for (int j = 0; j < 8; ++j) ssum += expf(r[j] - m);
#pragma unroll
        for (int off = 1; off <= 4; off <<= 1) ssum += __shfl_xor(ssum, off);
        float lse = m + logf(ssum);
        if (g == 0) {
            float4 o0 = make_float4(r[0] - lse, r[1] - lse, r[2] - lse, r[3] - lse);
            float4 o1 = make_float4(r[4] - lse, r[5] - lse, r[6] - lse, r[7] - lse);
            float* dst = outf + ((size_t)node << 6) + gl * 8;
            *(float4*)dst = o0;
            *(float4*)(dst + 4) = o1;
        }
    } else {
        if (g == 0) {
            union { uint4 u; __half2 h2[4]; } pk;
            pk.h2[0] = __floats2half2_rn(r[0], r[1]);
            pk.h2[1] = __floats2half2_rn(r[2], r[3]);
            pk.h2[2] = __floats2half2_rn(r[4], r[5]);
            pk.h2[3] = __floats2half2_rn(r[6], r[7]);
            *((uint4*)(acta + ((size_t)node << 6)) + gl) = pk.u;
        }
    }
}

// ---------------- launch ----------------

extern "C" void kernel_launch(void* const* d_in, const int* in_sizes, int n_in,
                              void* d_out, int out_size, void* d_ws, size_t ws_size,
                              hipStream_t stream) {
    const float* x = (const float*)d_in[0];
    const int* ei  = (const int*)d_in[1];   // harness delivers integers as int32
    const int* src = ei;
    const int* dst = ei + N_EDGES;

    const float* W[6];
    const float* b[6];
    for (int i = 0; i < 6; ++i) {
        W[i] = (const float*)d_in[2 + 2 * i];
        b[i] = (const float*)d_in[3 + 2 * i];
    }
    float* out = (float*)d_out;

    // workspace: rowptr [N+1] | dinv [N] | colv [E] | h_fp16 [N*64] | act_fp16 [N*64]
    // build-only arrays alias the h region (dead until first GEMM).
    char* p = (char*)d_ws;
    int*    rowptr = (int*)p;    p += (size_t)(N_NODES + 1) * 4;
    float*  dinv   = (float*)p;  p += (size_t)N_NODES * 4;
    int*    colv   = (int*)p;    p += (size_t)N_EDGES * 4;
    __half* h      = (__half*)p; p += (size_t)N_NODES * 64 * 2;   // 12.8 MB
    __half* act    = (__half*)p;                                   // 12.8 MB
    unsigned* bentry = (unsigned*)h;                       // 6.4 MB (aliases h)
    int*    ghist = (int*)(bentry + (size_t)N_EDGES);      // NB*64 ints (400 KB)
    int*    btot  = ghist + (size_t)NB * NBLK_S;           // NB ints
    int*    bbase = btot + NB;                             // NB ints

    const int nb_wave = (N_NODES + 3) / 4;      // aggregate: 1 node/wave
    const int nb_tile = (N_NODES + 63) / 64;    // gemm: 64 nodes/block

    // CSR build: counting sort by bucket, then in-bucket refine.
    k_hist<<<NBLK_S, 256, 0, stream>>>(dst, ghist);
    k_scanb<<<NB, 64, 0, stream>>>(ghist, btot);
    k_scant<<<1, 1024, 0, stream>>>(btot, bbase, rowptr);
    k_scatter<<<NBLK_S, 256, 0, stream>>>(src, dst, ghist, bbase, bentry);
    k_fill2<<<NB, 256, 0, stream>>>(btot, bbase, bentry, rowptr, dinv, colv);

    // 6 GCN layers; gemm(cur -> h), aggregate(h -> act / d_out)
    for (int l = 0; l < 6; ++l) {
        if (l == 0)
            k_gemm<128, 0><<<nb_tile, 256, 0, stream>>>(x, W[l], dinv, h);
        else
            k_gemm<64, 1><<<nb_tile, 256, 0, stream>>>(act, W[l], dinv, h);
        if (l == 5)
            k_aggregate<1><<<nb_wave, 256, 0, stream>>>(rowptr, colv, h, dinv, b[l], act, out);
        else
            k_aggregate<0><<<nb_wave, 256, 0, stream>>>(rowptr, colv, h, dinv, b[l], act, out);
    }
}

// Round 9
// 419.341 us; speedup vs baseline: 2.0783x; 1.2528x over previous
//
#include <hip/hip_runtime.h>
#include <hip/hip_fp16.h>
#include <math.h>

#define N_NODES 100000
#define N_EDGES 1600000
#define NB 1563          // ceil(N_NODES / 64) buckets, bucket = dst >> 6
#define CAP 2048         // LDS staging per bucket in k_fill2 (mean 1024, sd ~32)
#define NBLK_S 64        // scatter/hist blocks
#define CHUNK ((N_EDGES + NBLK_S - 1) / NBLK_S)   // 25000 edges per block

// ---------------- counting-sort CSR build ----------------

// Pass 1: per-block histogram over buckets (LDS), write ghist[b][blk].
__global__ __launch_bounds__(256) void k_hist(const int* __restrict__ dst,
                                              int* __restrict__ ghist) {
    __shared__ int hist[NB];
    int blk = blockIdx.x, t = threadIdx.x;
    for (int i = t; i < NB; i += 256) hist[i] = 0;
    __syncthreads();
    int beg = blk * CHUNK, end = min(beg + CHUNK, N_EDGES);
    for (int e = beg + t; e < end; e += 256)
        atomicAdd(&hist[dst[e] >> 6], 1);
    __syncthreads();
    for (int i = t; i < NB; i += 256) ghist[i * NBLK_S + blk] = hist[i];
}

// Pass 2: exclusive scan of the 64 block-counts within each bucket (1 wave).
__global__ void k_scanb(int* __restrict__ ghist, int* __restrict__ btot) {
    int b = blockIdx.x, t = threadIdx.x;
    int v = ghist[b * NBLK_S + t];
    int incl = v;
#pragma unroll
    for (int off = 1; off < 64; off <<= 1) {
        int a = __shfl_up(incl, off);
        if (t >= off) incl += a;
    }
    ghist[b * NBLK_S + t] = incl - v;
    if (t == 63) btot[b] = incl;
}

// Pass 3: exclusive scan of the 1563 bucket totals (single block, 2 chunks).
__global__ void k_scant(const int* __restrict__ btot, int* __restrict__ bbase,
                        int* __restrict__ rowptr) {
    __shared__ int s[1024];
    __shared__ int carry;
    int t = threadIdx.x;
    if (t == 0) carry = 0;
    __syncthreads();
    for (int chunk = 0; chunk < 2; ++chunk) {
        int i = chunk * 1024 + t;
        int v = (i < NB) ? btot[i] : 0;
        s[t] = v;
        __syncthreads();
        for (int off = 1; off < 1024; off <<= 1) {
            int a = (t >= off) ? s[t - off] : 0;
            __syncthreads();
            s[t] += a;
            __syncthreads();
        }
        if (i < NB) bbase[i] = carry + s[t] - v;
        int total = carry + s[1023];
        __syncthreads();
        if (t == 0) carry = total;
        __syncthreads();
    }
    if (t == 0) rowptr[N_NODES] = N_EDGES;
}

// Pass 4: scatter into bucket-sorted bentry. Each (block,bucket) region is
// exclusively owned by one block -> write lines fill from a single CU.
__global__ __launch_bounds__(256) void k_scatter(const int* __restrict__ src,
                                                 const int* __restrict__ dst,
                                                 const int* __restrict__ ghist,
                                                 const int* __restrict__ bbase,
                                                 unsigned* __restrict__ bentry) {
    __shared__ int cursor[NB];
    int blk = blockIdx.x, t = threadIdx.x;
    for (int i = t; i < NB; i += 256)
        cursor[i] = bbase[i] + ghist[i * NBLK_S + blk];
    __syncthreads();
    int beg = blk * CHUNK, end = min(beg + CHUNK, N_EDGES);
    for (int e = beg + t; e < end; e += 256) {
        int d = dst[e], s = src[e];
        int pos = atomicAdd(&cursor[d >> 6], 1);
        bentry[pos] = ((unsigned)(d & 63) << 17) | (unsigned)s;
    }
}

// Pass 5: one block per bucket; LDS histogram -> rowptr/dinv, LDS cursors ->
// colv scatter confined to the bucket's contiguous window.
__global__ __launch_bounds__(256) void k_fill2(const int* __restrict__ btot,
                                               const int* __restrict__ bbase,
                                               const unsigned* __restrict__ bentry,
                                               int* __restrict__ rowptr,
                                               float* __restrict__ dinv,
                                               int* __restrict__ colv) {
    __shared__ unsigned ent[CAP];
    __shared__ int hist[64];
    __shared__ int cursor[64];
    int b = blockIdx.x;
    int t = threadIdx.x;
    int cnt = btot[b]; if (cnt > CAP) cnt = CAP;
    int base = bbase[b];
    if (t < 64) hist[t] = 0;
    __syncthreads();
    const unsigned* be = bentry + base;
    for (int i = t; i < cnt; i += 256) {
        unsigned e = be[i];
        ent[i] = e;
        atomicAdd(&hist[e >> 17], 1);
    }
    __syncthreads();
    if (t < 64) {   // wave 0: scan the 64-bin histogram
        int v = hist[t];
        int incl = v;
#pragma unroll
        for (int off = 1; off < 64; off <<= 1) {
            int a = __shfl_up(incl, off);
            if (t >= off) incl += a;
        }
        int excl = incl - v;
        cursor[t] = excl;
        int node = (b << 6) + t;
        if (node < N_NODES) {
            rowptr[node] = base + excl;
            dinv[node] = rsqrtf((float)(v + 1));   // +1 self-loop
        }
    }
    __syncthreads();
    for (int i = t; i < cnt; i += 256) {
        unsigned e = ent[i];
        int pos = base + atomicAdd(&cursor[e >> 17], 1);
        colv[pos] = (int)(e & 0x1FFFF);
    }
}

// ---------------- tiled GEMM: h' = (in @ W) * dinv[node], fp16 out --------
// Block 256 threads = 64-node x 64-col tile; X-tile + W-chunk staged in LDS
// as fp32 (rows padded to 68 -> <=2-way bank aliasing). 4x4 register tile
// per thread. Input fp32 (layer 0) or fp16 (layers 1-5); output fp16.

template<int DIN, int HALF_IN>
__global__ __launch_bounds__(256) void k_gemm(const void* __restrict__ in,
                                              const float* __restrict__ W,
                                              const float* __restrict__ dinv,
                                              __half* __restrict__ h) {
    __shared__ float sX[64 * 68];
    __shared__ float sW[64 * 68];
    int tid  = threadIdx.x;
    int lane = tid & 63, wave = tid >> 6;
    int node0 = blockIdx.x * 64;
    int r_base = wave * 16 + 4 * (lane >> 4);
    int c_base = 4 * (lane & 15);

    float acc[4][4] = {};

#pragma unroll
    for (int kc = 0; kc < DIN / 64; ++kc) {
#pragma unroll
        for (int i = 0; i < 4; ++i) {
            int idx = tid + i * 256;
            int row = idx >> 4;
            int j4  = (idx & 15) * 4;
            int nr  = node0 + row; if (nr >= N_NODES) nr = N_NODES - 1;
            if (HALF_IN) {
                union { uint2 u; __half2 h2[2]; } cv;
                cv.u = *(const uint2*)((const __half*)in + (size_t)nr * DIN + kc * 64 + j4);
                float2 f0 = __half22float2(cv.h2[0]);
                float2 f1 = __half22float2(cv.h2[1]);
                sX[row * 68 + j4 + 0] = f0.x; sX[row * 68 + j4 + 1] = f0.y;
                sX[row * 68 + j4 + 2] = f1.x; sX[row * 68 + j4 + 3] = f1.y;
            } else {
                *(float4*)(sX + row * 68 + j4) =
                    *(const float4*)((const float*)in + (size_t)nr * DIN + kc * 64 + j4);
            }
            *(float4*)(sW + row * 68 + j4) =
                *(const float4*)(W + (size_t)(kc * 64 + row) * 64 + j4);
        }
        __syncthreads();

#pragma unroll 16
        for (int k = 0; k < 64; ++k) {
            float4 wv = *(const float4*)(sW + k * 68 + c_base);
            float x0 = sX[(r_base + 0) * 68 + k];
            float x1 = sX[(r_base + 1) * 68 + k];
            float x2 = sX[(r_base + 2) * 68 + k];
            float x3 = sX[(r_base + 3) * 68 + k];
            acc[0][0] = fmaf(x0, wv.x, acc[0][0]); acc[0][1] = fmaf(x0, wv.y, acc[0][1]);
            acc[0][2] = fmaf(x0, wv.z, acc[0][2]); acc[0][3] = fmaf(x0, wv.w, acc[0][3]);
            acc[1][0] = fmaf(x1, wv.x, acc[1][0]); acc[1][1] = fmaf(x1, wv.y, acc[1][1]);
            acc[1][2] = fmaf(x1, wv.z, acc[1][2]); acc[1][3] = fmaf(x1, wv.w, acc[1][3]);
            acc[2][0] = fmaf(x2, wv.x, acc[2][0]); acc[2][1] = fmaf(x2, wv.y, acc[2][1]);
            acc[2][2] = fmaf(x2, wv.z, acc[2][2]); acc[2][3] = fmaf(x2, wv.w, acc[2][3]);
            acc[3][0] = fmaf(x3, wv.x, acc[3][0]); acc[3][1] = fmaf(x3, wv.y, acc[3][1]);
            acc[3][2] = fmaf(x3, wv.z, acc[3][2]); acc[3][3] = fmaf(x3, wv.w, acc[3][3]);
        }
        __syncthreads();
    }

#pragma unroll
    for (int i = 0; i < 4; ++i) {
        int r = node0 + r_base + i;
        if (r < N_NODES) {
            float dn = dinv[r];
            union { uint2 u; __half2 h2[2]; } pk;
            pk.h2[0] = __floats2half2_rn(acc[i][0] * dn, acc[i][1] * dn);
            pk.h2[1] = __floats2half2_rn(acc[i][2] * dn, acc[i][3] * dn);
            *(uint2*)(h + ((size_t)r << 6) + c_base) = pk.u;
        }
    }
}

// ---------------- fused aggregate (fp16 gather, packed fp16 accumulate) ---
// out[d] = relu( dinv[d] * (sum_{s in N(d)} h'[s] + h'[d]) + bias )
// Quarter-wave (16 lanes) per node; lane owns 4 columns (8B of each 128B
// row). Serial edge loop, unroll x4 (independent loads), v_pk_add_f16
// accumulate, fp32 epilogue. No cross-lane reduce needed.

template<int LAST>
__global__ __launch_bounds__(256) void k_aggregate(const int* __restrict__ rowptr,
                                                   const int* __restrict__ colv,
                                                   const __half* __restrict__ h,
                                                   const float* __restrict__ dinv,
                                                   const float* __restrict__ bias,
                                                   __half* __restrict__ acta,
                                                   float* __restrict__ outf) {
    int tid  = threadIdx.x;
    int node = blockIdx.x * 16 + (tid >> 4);
    if (node >= N_NODES) return;
    int ql = tid & 15;                          // owns cols ql*4 .. ql*4+3

    int beg = rowptr[node], end = rowptr[node + 1];
    const __half* hp = h + (ql << 2);           // column offset within rows

    __half2 a0 = __floats2half2_rn(0.f, 0.f), a1 = a0, b0 = a0, b1 = a0;
    int k = beg;
    for (; k + 4 <= end; k += 4) {
        int s0 = colv[k], s1 = colv[k + 1], s2 = colv[k + 2], s3 = colv[k + 3];
        union { uint2 u; __half2 h2[2]; } v0, v1, v2, v3;
        v0.u = *(const uint2*)(hp + ((size_t)s0 << 6));
        v1.u = *(const uint2*)(hp + ((size_t)s1 << 6));
        v2.u = *(const uint2*)(hp + ((size_t)s2 << 6));
        v3.u = *(const uint2*)(hp + ((size_t)s3 << 6));
        a0 = __hadd2(a0, v0.h2[0]); a1 = __hadd2(a1, v0.h2[1]);
        b0 = __hadd2(b0, v1.h2[0]); b1 = __hadd2(b1, v1.h2[1]);
        a0 = __hadd2(a0, v2.h2[0]); a1 = __hadd2(a1, v2.h2[1]);
        b0 = __hadd2(b0, v3.h2[0]); b1 = __hadd2(b1, v3.h2[1]);
    }
    for (; k < end; ++k) {
        int s0 = colv[k];
        union { uint2 u; __half2 h2[2]; } v0;
        v0.u = *(const uint2*)(hp + ((size_t)s0 << 6));
        a0 = __hadd2(a0, v0.h2[0]); a1 = __hadd2(a1, v0.h2[1]);
    }
    a0 = __hadd2(a0, b0); a1 = __hadd2(a1, b1);

    // fp32 epilogue: self-loop + normalize + bias + relu
    float2 f0 = __half22float2(a0), f1 = __half22float2(a1);
    union { uint2 u; __half2 h2[2]; } sv;
    sv.u = *(const uint2*)(hp + ((size_t)node << 6));
    float2 s0f = __half22float2(sv.h2[0]), s1f = __half22float2(sv.h2[1]);
    float dn = dinv[node];
    float4 bv = ((const float4*)bias)[ql];
    float r0 = fmaxf(fmaf(f0.x + s0f.x, dn, bv.x), 0.f);
    float r1 = fmaxf(fmaf(f0.y + s0f.y, dn, bv.y), 0.f);
    float r2 = fmaxf(fmaf(f1.x + s1f.x, dn, bv.z), 0.f);
    float r3 = fmaxf(fmaf(f1.y + s1f.y, dn, bv.w), 0.f);

    if (LAST) {
        // log-softmax across the quarter's 16 lanes (offsets 1,2,4,8)
        float m = fmaxf(fmaxf(r0, r1), fmaxf(r2, r3));
#pragma unroll
        for (int off = 1; off <= 8; off <<= 1) m = fmaxf(m, __shfl_xor(m, off));
        float ss = expf(r0 - m) + expf(r1 - m) + expf(r2 - m) + expf(r3 - m);
#pragma unroll
        for (int off = 1; off <= 8; off <<= 1) ss += __shfl_xor(ss, off);
        float lse = m + logf(ss);
        *(float4*)(outf + ((size_t)node << 6) + (ql << 2)) =
            make_float4(r0 - lse, r1 - lse, r2 - lse, r3 - lse);
    } else {
        union { uint2 u; __half2 h2[2]; } pk;
        pk.h2[0] = __floats2half2_rn(r0, r1);
        pk.h2[1] = __floats2half2_rn(r2, r3);
        *(uint2*)(acta + ((size_t)node << 6) + (ql << 2)) = pk.u;
    }
}

// ---------------- launch ----------------

extern "C" void kernel_launch(void* const* d_in, const int* in_sizes, int n_in,
                              void* d_out, int out_size, void* d_ws, size_t ws_size,
                              hipStream_t stream) {
    const float* x = (const float*)d_in[0];
    const int* ei  = (const int*)d_in[1];   // harness delivers integers as int32
    const int* src = ei;
    const int* dst = ei + N_EDGES;

    const float* W[6];
    const float* b[6];
    for (int i = 0; i < 6; ++i) {
        W[i] = (const float*)d_in[2 + 2 * i];
        b[i] = (const float*)d_in[3 + 2 * i];
    }
    float* out = (float*)d_out;

    // workspace: h_fp16 [N*64] | act_fp16 [N*64] | rowptr [N+1] | dinv [N] |
    // colv [E]. h first -> all vector gathers naturally aligned.
    // build-only arrays alias the h region (dead until first GEMM).
    char* p = (char*)d_ws;
    __half* h      = (__half*)p; p += (size_t)N_NODES * 64 * 2;   // 12.8 MB
    __half* act    = (__half*)p; p += (size_t)N_NODES * 64 * 2;   // 12.8 MB
    int*    rowptr = (int*)p;    p += (size_t)(N_NODES + 1) * 4;
    float*  dinv   = (float*)p;  p += (size_t)N_NODES * 4;
    int*    colv   = (int*)p;
    unsigned* bentry = (unsigned*)h;                       // 6.4 MB (aliases h)
    int*    ghist = (int*)(bentry + (size_t)N_EDGES);      // NB*64 ints (400 KB)
    int*    btot  = ghist + (size_t)NB * NBLK_S;           // NB ints
    int*    bbase = btot + NB;                             // NB ints

    const int nb_q    = (N_NODES + 15) / 16;    // aggregate: 1 node/quarter-wave
    const int nb_tile = (N_NODES + 63) / 64;    // gemm: 64 nodes/block

    // CSR build: counting sort by bucket, then in-bucket refine.
    k_hist<<<NBLK_S, 256, 0, stream>>>(dst, ghist);
    k_scanb<<<NB, 64, 0, stream>>>(ghist, btot);
    k_scant<<<1, 1024, 0, stream>>>(btot, bbase, rowptr);
    k_scatter<<<NBLK_S, 256, 0, stream>>>(src, dst, ghist, bbase, bentry);
    k_fill2<<<NB, 256, 0, stream>>>(btot, bbase, bentry, rowptr, dinv, colv);

    // 6 GCN layers; gemm(cur -> h), aggregate(h -> act / d_out)
    for (int l = 0; l < 6; ++l) {
        if (l == 0)
            k_gemm<128, 0><<<nb_tile, 256, 0, stream>>>(x, W[l], dinv, h);
        else
            k_gemm<64, 1><<<nb_tile, 256, 0, stream>>>(act, W[l], dinv, h);
        if (l == 5)
            k_aggregate<1><<<nb_q, 256, 0, stream>>>(rowptr, colv, h, dinv, b[l], act, out);
        else
            k_aggregate<0><<<nb_q, 256, 0, stream>>>(rowptr, colv, h, dinv, b[l], act, out);
    }
}

// Round 10
// 382.026 us; speedup vs baseline: 2.2813x; 1.0977x over previous
//
#include <hip/hip_runtime.h>
#include <hip/hip_fp16.h>
#include <math.h>

#define N_NODES 100000
#define N_EDGES 1600000
#define NB 1563          // ceil(N_NODES / 64) buckets, bucket = dst >> 6
#define CAP 2048         // LDS staging per bucket in k_fill2 (mean 1024, sd ~32)
#define NBLK_S 128       // scatter/hist blocks
#define CHUNK (N_EDGES / NBLK_S)   // 12500 edges per block (divides exactly)

// ---------------- counting-sort CSR build ----------------

// Pass 1: per-block histogram over buckets (LDS), int4 x4-unrolled.
__global__ __launch_bounds__(256) void k_hist(const int* __restrict__ dst,
                                              int* __restrict__ ghist) {
    __shared__ int hist[NB];
    int blk = blockIdx.x, t = threadIdx.x;
    for (int i = t; i < NB; i += 256) hist[i] = 0;
    __syncthreads();
    const int4* dq = (const int4*)(dst + blk * CHUNK);   // 50000B chunks, 16B-aligned
    const int nq = CHUNK >> 2;                            // 3125 quads
    for (int i = t; i < nq; i += 256) {
        int4 d = dq[i];
        atomicAdd(&hist[d.x >> 6], 1);
        atomicAdd(&hist[d.y >> 6], 1);
        atomicAdd(&hist[d.z >> 6], 1);
        atomicAdd(&hist[d.w >> 6], 1);
    }
    __syncthreads();
    for (int i = t; i < NB; i += 256) ghist[i * NBLK_S + blk] = hist[i];
}

// Pass 2: exclusive scan of the 128 block-counts within each bucket.
__global__ void k_scanb(int* __restrict__ ghist, int* __restrict__ btot) {
    __shared__ int s[NBLK_S];
    int b = blockIdx.x, t = threadIdx.x;
    int v = ghist[b * NBLK_S + t];
    s[t] = v;
    __syncthreads();
    for (int off = 1; off < NBLK_S; off <<= 1) {
        int a = (t >= off) ? s[t - off] : 0;
        __syncthreads();
        s[t] += a;
        __syncthreads();
    }
    ghist[b * NBLK_S + t] = s[t] - v;
    if (t == NBLK_S - 1) btot[b] = s[t];
}

// Pass 3: exclusive scan of the 1563 bucket totals (single block, 2 chunks).
__global__ void k_scant(const int* __restrict__ btot, int* __restrict__ bbase,
                        int* __restrict__ rowptr) {
    __shared__ int s[1024];
    __shared__ int carry;
    int t = threadIdx.x;
    if (t == 0) carry = 0;
    __syncthreads();
    for (int chunk = 0; chunk < 2; ++chunk) {
        int i = chunk * 1024 + t;
        int v = (i < NB) ? btot[i] : 0;
        s[t] = v;
        __syncthreads();
        for (int off = 1; off < 1024; off <<= 1) {
            int a = (t >= off) ? s[t - off] : 0;
            __syncthreads();
            s[t] += a;
            __syncthreads();
        }
        if (i < NB) bbase[i] = carry + s[t] - v;
        int total = carry + s[1023];
        __syncthreads();
        if (t == 0) carry = total;
        __syncthreads();
    }
    if (t == 0) rowptr[N_NODES] = N_EDGES;
}

// Pass 4: scatter into bucket-sorted bentry, int4 x4-unrolled (4 independent
// LDS atomics + stores in flight). Each (block,bucket) region exclusive.
__global__ __launch_bounds__(256) void k_scatter(const int* __restrict__ src,
                                                 const int* __restrict__ dst,
                                                 const int* __restrict__ ghist,
                                                 const int* __restrict__ bbase,
                                                 unsigned* __restrict__ bentry) {
    __shared__ int cursor[NB];
    int blk = blockIdx.x, t = threadIdx.x;
    for (int i = t; i < NB; i += 256)
        cursor[i] = bbase[i] + ghist[i * NBLK_S + blk];
    __syncthreads();
    const int4* dq = (const int4*)(dst + blk * CHUNK);
    const int4* sq = (const int4*)(src + blk * CHUNK);
    const int nq = CHUNK >> 2;
    for (int i = t; i < nq; i += 256) {
        int4 d = dq[i];
        int4 s = sq[i];
        int p0 = atomicAdd(&cursor[d.x >> 6], 1);
        int p1 = atomicAdd(&cursor[d.y >> 6], 1);
        int p2 = atomicAdd(&cursor[d.z >> 6], 1);
        int p3 = atomicAdd(&cursor[d.w >> 6], 1);
        bentry[p0] = ((unsigned)(d.x & 63) << 17) | (unsigned)s.x;
        bentry[p1] = ((unsigned)(d.y & 63) << 17) | (unsigned)s.y;
        bentry[p2] = ((unsigned)(d.z & 63) << 17) | (unsigned)s.z;
        bentry[p3] = ((unsigned)(d.w & 63) << 17) | (unsigned)s.w;
    }
}

// Pass 5: one block per bucket; LDS histogram -> rowptr/dinv, LDS cursors ->
// colv scatter confined to the bucket's contiguous window.
__global__ __launch_bounds__(256) void k_fill2(const int* __restrict__ btot,
                                               const int* __restrict__ bbase,
                                               const unsigned* __restrict__ bentry,
                                               int* __restrict__ rowptr,
                                               float* __restrict__ dinv,
                                               int* __restrict__ colv) {
    __shared__ unsigned ent[CAP];
    __shared__ int hist[64];
    __shared__ int cursor[64];
    int b = blockIdx.x;
    int t = threadIdx.x;
    int cnt = btot[b]; if (cnt > CAP) cnt = CAP;
    int base = bbase[b];
    if (t < 64) hist[t] = 0;
    __syncthreads();
    const unsigned* be = bentry + base;
    for (int i = t; i < cnt; i += 256) {
        unsigned e = be[i];
        ent[i] = e;
        atomicAdd(&hist[e >> 17], 1);
    }
    __syncthreads();
    if (t < 64) {   // wave 0: scan the 64-bin histogram
        int v = hist[t];
        int incl = v;
#pragma unroll
        for (int off = 1; off < 64; off <<= 1) {
            int a = __shfl_up(incl, off);
            if (t >= off) incl += a;
        }
        int excl = incl - v;
        cursor[t] = excl;
        int node = (b << 6) + t;
        if (node < N_NODES) {
            rowptr[node] = base + excl;
            dinv[node] = rsqrtf((float)(v + 1));   // +1 self-loop
        }
    }
    __syncthreads();
    for (int i = t; i < cnt; i += 256) {
        unsigned e = ent[i];
        int pos = base + atomicAdd(&cursor[e >> 17], 1);
        colv[pos] = (int)(e & 0x1FFFF);
    }
}

// ---------------- tiled GEMM: h' = (in @ W) * dinv[node], fp16 out --------
// Block 256 threads = 64-node x 64-col tile; X-tile + W-chunk staged in LDS
// as fp32 (rows padded to 68 -> <=2-way bank aliasing). 4x4 register tile
// per thread. Input fp32 (layer 0) or fp16 (layers 1-5); output fp16.

template<int DIN, int HALF_IN>
__global__ __launch_bounds__(256) void k_gemm(const void* __restrict__ in,
                                              const float* __restrict__ W,
                                              const float* __restrict__ dinv,
                                              __half* __restrict__ h) {
    __shared__ float sX[64 * 68];
    __shared__ float sW[64 * 68];
    int tid  = threadIdx.x;
    int lane = tid & 63, wave = tid >> 6;
    int node0 = blockIdx.x * 64;
    int r_base = wave * 16 + 4 * (lane >> 4);
    int c_base = 4 * (lane & 15);

    float acc[4][4] = {};

#pragma unroll
    for (int kc = 0; kc < DIN / 64; ++kc) {
#pragma unroll
        for (int i = 0; i < 4; ++i) {
            int idx = tid + i * 256;
            int row = idx >> 4;
            int j4  = (idx & 15) * 4;
            int nr  = node0 + row; if (nr >= N_NODES) nr = N_NODES - 1;
            if (HALF_IN) {
                union { uint2 u; __half2 h2[2]; } cv;
                cv.u = *(const uint2*)((const __half*)in + (size_t)nr * DIN + kc * 64 + j4);
                float2 f0 = __half22float2(cv.h2[0]);
                float2 f1 = __half22float2(cv.h2[1]);
                sX[row * 68 + j4 + 0] = f0.x; sX[row * 68 + j4 + 1] = f0.y;
                sX[row * 68 + j4 + 2] = f1.x; sX[row * 68 + j4 + 3] = f1.y;
            } else {
                *(float4*)(sX + row * 68 + j4) =
                    *(const float4*)((const float*)in + (size_t)nr * DIN + kc * 64 + j4);
            }
            *(float4*)(sW + row * 68 + j4) =
                *(const float4*)(W + (size_t)(kc * 64 + row) * 64 + j4);
        }
        __syncthreads();

#pragma unroll 16
        for (int k = 0; k < 64; ++k) {
            float4 wv = *(const float4*)(sW + k * 68 + c_base);
            float x0 = sX[(r_base + 0) * 68 + k];
            float x1 = sX[(r_base + 1) * 68 + k];
            float x2 = sX[(r_base + 2) * 68 + k];
            float x3 = sX[(r_base + 3) * 68 + k];
            acc[0][0] = fmaf(x0, wv.x, acc[0][0]); acc[0][1] = fmaf(x0, wv.y, acc[0][1]);
            acc[0][2] = fmaf(x0, wv.z, acc[0][2]); acc[0][3] = fmaf(x0, wv.w, acc[0][3]);
            acc[1][0] = fmaf(x1, wv.x, acc[1][0]); acc[1][1] = fmaf(x1, wv.y, acc[1][1]);
            acc[1][2] = fmaf(x1, wv.z, acc[1][2]); acc[1][3] = fmaf(x1, wv.w, acc[1][3]);
            acc[2][0] = fmaf(x2, wv.x, acc[2][0]); acc[2][1] = fmaf(x2, wv.y, acc[2][1]);
            acc[2][2] = fmaf(x2, wv.z, acc[2][2]); acc[2][3] = fmaf(x2, wv.w, acc[2][3]);
            acc[3][0] = fmaf(x3, wv.x, acc[3][0]); acc[3][1] = fmaf(x3, wv.y, acc[3][1]);
            acc[3][2] = fmaf(x3, wv.z, acc[3][2]); acc[3][3] = fmaf(x3, wv.w, acc[3][3]);
        }
        __syncthreads();
    }

#pragma unroll
    for (int i = 0; i < 4; ++i) {
        int r = node0 + r_base + i;
        if (r < N_NODES) {
            float dn = dinv[r];
            union { uint2 u; __half2 h2[2]; } pk;
            pk.h2[0] = __floats2half2_rn(acc[i][0] * dn, acc[i][1] * dn);
            pk.h2[1] = __floats2half2_rn(acc[i][2] * dn, acc[i][3] * dn);
            *(uint2*)(h + ((size_t)r << 6) + c_base) = pk.u;
        }
    }
}

// ---------------- fused aggregate (fp16 gather, packed fp16 accumulate) ---
// out[d] = relu( dinv[d] * (sum_{s in N(d)} h'[s] + h'[d]) + bias )
// Quarter-wave (16 lanes) per node; lane owns 4 columns (8B of each 128B
// row). Serial edge loop, unroll x4 (independent loads), v_pk_add_f16
// accumulate, fp32 epilogue. No cross-lane reduce needed.

template<int LAST>
__global__ __launch_bounds__(256) void k_aggregate(const int* __restrict__ rowptr,
                                                   const int* __restrict__ colv,
                                                   const __half* __restrict__ h,
                                                   const float* __restrict__ dinv,
                                                   const float* __restrict__ bias,
                                                   __half* __restrict__ acta,
                                                   float* __restrict__ outf) {
    int tid  = threadIdx.x;
    int node = blockIdx.x * 16 + (tid >> 4);
    if (node >= N_NODES) return;
    int ql = tid & 15;                          // owns cols ql*4 .. ql*4+3

    int beg = rowptr[node], end = rowptr[node + 1];
    const __half* hp = h + (ql << 2);           // column offset within rows

    __half2 a0 = __floats2half2_rn(0.f, 0.f), a1 = a0, b0 = a0, b1 = a0;
    int k = beg;
    for (; k + 4 <= end; k += 4) {
        int s0 = colv[k], s1 = colv[k + 1], s2 = colv[k + 2], s3 = colv[k + 3];
        union { uint2 u; __half2 h2[2]; } v0, v1, v2, v3;
        v0.u = *(const uint2*)(hp + ((size_t)s0 << 6));
        v1.u = *(const uint2*)(hp + ((size_t)s1 << 6));
        v2.u = *(const uint2*)(hp + ((size_t)s2 << 6));
        v3.u = *(const uint2*)(hp + ((size_t)s3 << 6));
        a0 = __hadd2(a0, v0.h2[0]); a1 = __hadd2(a1, v0.h2[1]);
        b0 = __hadd2(b0, v1.h2[0]); b1 = __hadd2(b1, v1.h2[1]);
        a0 = __hadd2(a0, v2.h2[0]); a1 = __hadd2(a1, v2.h2[1]);
        b0 = __hadd2(b0, v3.h2[0]); b1 = __hadd2(b1, v3.h2[1]);
    }
    for (; k < end; ++k) {
        int s0 = colv[k];
        union { uint2 u; __half2 h2[2]; } v0;
        v0.u = *(const uint2*)(hp + ((size_t)s0 << 6));
        a0 = __hadd2(a0, v0.h2[0]); a1 = __hadd2(a1, v0.h2[1]);
    }
    a0 = __hadd2(a0, b0); a1 = __hadd2(a1, b1);

    // fp32 epilogue: self-loop + normalize + bias + relu
    float2 f0 = __half22float2(a0), f1 = __half22float2(a1);
    union { uint2 u; __half2 h2[2]; } sv;
    sv.u = *(const uint2*)(hp + ((size_t)node << 6));
    float2 s0f = __half22float2(sv.h2[0]), s1f = __half22float2(sv.h2[1]);
    float dn = dinv[node];
    float4 bv = ((const float4*)bias)[ql];
    float r0 = fmaxf(fmaf(f0.x + s0f.x, dn, bv.x), 0.f);
    float r1 = fmaxf(fmaf(f0.y + s0f.y, dn, bv.y), 0.f);
    float r2 = fmaxf(fmaf(f1.x + s1f.x, dn, bv.z), 0.f);
    float r3 = fmaxf(fmaf(f1.y + s1f.y, dn, bv.w), 0.f);

    if (LAST) {
        // log-softmax across the quarter's 16 lanes (offsets 1,2,4,8)
        float m = fmaxf(fmaxf(r0, r1), fmaxf(r2, r3));
#pragma unroll
        for (int off = 1; off <= 8; off <<= 1) m = fmaxf(m, __shfl_xor(m, off));
        float ss = expf(r0 - m) + expf(r1 - m) + expf(r2 - m) + expf(r3 - m);
#pragma unroll
        for (int off = 1; off <= 8; off <<= 1) ss += __shfl_xor(ss, off);
        float lse = m + logf(ss);
        *(float4*)(outf + ((size_t)node << 6) + (ql << 2)) =
            make_float4(r0 - lse, r1 - lse, r2 - lse, r3 - lse);
    } else {
        union { uint2 u; __half2 h2[2]; } pk;
        pk.h2[0] = __floats2half2_rn(r0, r1);
        pk.h2[1] = __floats2half2_rn(r2, r3);
        *(uint2*)(acta + ((size_t)node << 6) + (ql << 2)) = pk.u;
    }
}

// ---------------- launch ----------------

extern "C" void kernel_launch(void* const* d_in, const int* in_sizes, int n_in,
                              void* d_out, int out_size, void* d_ws, size_t ws_size,
                              hipStream_t stream) {
    const float* x = (const float*)d_in[0];
    const int* ei  = (const int*)d_in[1];   // harness delivers integers as int32
    const int* src = ei;
    const int* dst = ei + N_EDGES;

    const float* W[6];
    const float* b[6];
    for (int i = 0; i < 6; ++i) {
        W[i] = (const float*)d_in[2 + 2 * i];
        b[i] = (const float*)d_in[3 + 2 * i];
    }
    float* out = (float*)d_out;

    // workspace: h_fp16 [N*64] | act_fp16 [N*64] | rowptr [N+1] | dinv [N] |
    // colv [E]. h first -> all vector gathers naturally aligned.
    // build-only arrays alias the h region (dead until first GEMM).
    char* p = (char*)d_ws;
    __half* h      = (__half*)p; p += (size_t)N_NODES * 64 * 2;   // 12.8 MB
    __half* act    = (__half*)p; p += (size_t)N_NODES * 64 * 2;   // 12.8 MB
    int*    rowptr = (int*)p;    p += (size_t)(N_NODES + 1) * 4;
    float*  dinv   = (float*)p;  p += (size_t)N_NODES * 4;
    int*    colv   = (int*)p;
    unsigned* bentry = (unsigned*)h;                       // 6.4 MB (aliases h)
    int*    ghist = (int*)(bentry + (size_t)N_EDGES);      // NB*128 ints (800 KB)
    int*    btot  = ghist + (size_t)NB * NBLK_S;           // NB ints
    int*    bbase = btot + NB;                             // NB ints

    const int nb_q    = (N_NODES + 15) / 16;    // aggregate: 1 node/quarter-wave
    const int nb_tile = (N_NODES + 63) / 64;    // gemm: 64 nodes/block

    // CSR build: counting sort by bucket, then in-bucket refine.
    k_hist<<<NBLK_S, 256, 0, stream>>>(dst, ghist);
    k_scanb<<<NB, NBLK_S, 0, stream>>>(ghist, btot);
    k_scant<<<1, 1024, 0, stream>>>(btot, bbase, rowptr);
    k_scatter<<<NBLK_S, 256, 0, stream>>>(src, dst, ghist, bbase, bentry);
    k_fill2<<<NB, 256, 0, stream>>>(btot, bbase, bentry, rowptr, dinv, colv);

    // 6 GCN layers; gemm(cur -> h), aggregate(h -> act / d_out)
    for (int l = 0; l < 6; ++l) {
        if (l == 0)
            k_gemm<128, 0><<<nb_tile, 256, 0, stream>>>(x, W[l], dinv, h);
        else
            k_gemm<64, 1><<<nb_tile, 256, 0, stream>>>(act, W[l], dinv, h);
        if (l == 5)
            k_aggregate<1><<<nb_q, 256, 0, stream>>>(rowptr, colv, h, dinv, b[l], act, out);
        else
            k_aggregate<0><<<nb_q, 256, 0, stream>>>(rowptr, colv, h, dinv, b[l], act, out);
    }
}

// Round 11
// 381.869 us; speedup vs baseline: 2.2822x; 1.0004x over previous
//
#include <hip/hip_runtime.h>
#include <hip/hip_fp16.h>
#include <math.h>

#define N_NODES 100000
#define N_EDGES 1600000
#define NB 1563          // ceil(N_NODES / 64) buckets, bucket = dst >> 6
#define CAP 2048         // LDS staging per bucket in k_fill2 (mean 1024, sd ~32)
#define NBLK_S 128       // scatter/hist blocks
#define CHUNK (N_EDGES / NBLK_S)   // 12500 edges per block (divides exactly)

typedef _Float16 half8_t __attribute__((ext_vector_type(8)));
typedef float floatx4 __attribute__((ext_vector_type(4)));

// ---------------- counting-sort CSR build ----------------

__global__ __launch_bounds__(256) void k_hist(const int* __restrict__ dst,
                                              int* __restrict__ ghist) {
    __shared__ int hist[NB];
    int blk = blockIdx.x, t = threadIdx.x;
    for (int i = t; i < NB; i += 256) hist[i] = 0;
    __syncthreads();
    const int4* dq = (const int4*)(dst + blk * CHUNK);
    const int nq = CHUNK >> 2;
    for (int i = t; i < nq; i += 256) {
        int4 d = dq[i];
        atomicAdd(&hist[d.x >> 6], 1);
        atomicAdd(&hist[d.y >> 6], 1);
        atomicAdd(&hist[d.z >> 6], 1);
        atomicAdd(&hist[d.w >> 6], 1);
    }
    __syncthreads();
    for (int i = t; i < NB; i += 256) ghist[i * NBLK_S + blk] = hist[i];
}

__global__ void k_scanb(int* __restrict__ ghist, int* __restrict__ btot) {
    __shared__ int s[NBLK_S];
    int b = blockIdx.x, t = threadIdx.x;
    int v = ghist[b * NBLK_S + t];
    s[t] = v;
    __syncthreads();
    for (int off = 1; off < NBLK_S; off <<= 1) {
        int a = (t >= off) ? s[t - off] : 0;
        __syncthreads();
        s[t] += a;
        __syncthreads();
    }
    ghist[b * NBLK_S + t] = s[t] - v;
    if (t == NBLK_S - 1) btot[b] = s[t];
}

__global__ void k_scant(const int* __restrict__ btot, int* __restrict__ bbase,
                        int* __restrict__ rowptr) {
    __shared__ int s[1024];
    __shared__ int carry;
    int t = threadIdx.x;
    if (t == 0) carry = 0;
    __syncthreads();
    for (int chunk = 0; chunk < 2; ++chunk) {
        int i = chunk * 1024 + t;
        int v = (i < NB) ? btot[i] : 0;
        s[t] = v;
        __syncthreads();
        for (int off = 1; off < 1024; off <<= 1) {
            int a = (t >= off) ? s[t - off] : 0;
            __syncthreads();
            s[t] += a;
            __syncthreads();
        }
        if (i < NB) bbase[i] = carry + s[t] - v;
        int total = carry + s[1023];
        __syncthreads();
        if (t == 0) carry = total;
        __syncthreads();
    }
    if (t == 0) rowptr[N_NODES] = N_EDGES;
}

__global__ __launch_bounds__(256) void k_scatter(const int* __restrict__ src,
                                                 const int* __restrict__ dst,
                                                 const int* __restrict__ ghist,
                                                 const int* __restrict__ bbase,
                                                 unsigned* __restrict__ bentry) {
    __shared__ int cursor[NB];
    int blk = blockIdx.x, t = threadIdx.x;
    for (int i = t; i < NB; i += 256)
        cursor[i] = bbase[i] + ghist[i * NBLK_S + blk];
    __syncthreads();
    const int4* dq = (const int4*)(dst + blk * CHUNK);
    const int4* sq = (const int4*)(src + blk * CHUNK);
    const int nq = CHUNK >> 2;
    for (int i = t; i < nq; i += 256) {
        int4 d = dq[i];
        int4 s = sq[i];
        int p0 = atomicAdd(&cursor[d.x >> 6], 1);
        int p1 = atomicAdd(&cursor[d.y >> 6], 1);
        int p2 = atomicAdd(&cursor[d.z >> 6], 1);
        int p3 = atomicAdd(&cursor[d.w >> 6], 1);
        bentry[p0] = ((unsigned)(d.x & 63) << 17) | (unsigned)s.x;
        bentry[p1] = ((unsigned)(d.y & 63) << 17) | (unsigned)s.y;
        bentry[p2] = ((unsigned)(d.z & 63) << 17) | (unsigned)s.z;
        bentry[p3] = ((unsigned)(d.w & 63) << 17) | (unsigned)s.w;
    }
}

__global__ __launch_bounds__(256) void k_fill2(const int* __restrict__ btot,
                                               const int* __restrict__ bbase,
                                               const unsigned* __restrict__ bentry,
                                               int* __restrict__ rowptr,
                                               float* __restrict__ dinv,
                                               int* __restrict__ colv) {
    __shared__ unsigned ent[CAP];
    __shared__ int hist[64];
    __shared__ int cursor[64];
    int b = blockIdx.x;
    int t = threadIdx.x;
    int cnt = btot[b]; if (cnt > CAP) cnt = CAP;
    int base = bbase[b];
    if (t < 64) hist[t] = 0;
    __syncthreads();
    const unsigned* be = bentry + base;
    for (int i = t; i < cnt; i += 256) {
        unsigned e = be[i];
        ent[i] = e;
        atomicAdd(&hist[e >> 17], 1);
    }
    __syncthreads();
    if (t < 64) {
        int v = hist[t];
        int incl = v;
#pragma unroll
        for (int off = 1; off < 64; off <<= 1) {
            int a = __shfl_up(incl, off);
            if (t >= off) incl += a;
        }
        int excl = incl - v;
        cursor[t] = excl;
        int node = (b << 6) + t;
        if (node < N_NODES) {
            rowptr[node] = base + excl;
            dinv[node] = rsqrtf((float)(v + 1));   // +1 self-loop
        }
    }
    __syncthreads();
    for (int i = t; i < cnt; i += 256) {
        unsigned e = ent[i];
        int pos = base + atomicAdd(&cursor[e >> 17], 1);
        colv[pos] = (int)(e & 0x1FFFF);
    }
}

// ---------------- weight prep: Wt[l][col][k] = (fp16) W[l][k][col] ---------

__global__ void k_prepw(const float* __restrict__ W1, const float* __restrict__ W2,
                        const float* __restrict__ W3, const float* __restrict__ W4,
                        const float* __restrict__ W5, const float* __restrict__ W6,
                        __half* __restrict__ wt) {
    int l = blockIdx.x;
    const float* W = (l == 0) ? W1 : (l == 1) ? W2 : (l == 2) ? W3
                   : (l == 3) ? W4 : (l == 4) ? W5 : W6;
    int din = (l == 0) ? 128 : 64;
    __half* dstp = wt + ((l == 0) ? 0 : 8192 + (l - 1) * 4096);
    int n = 64 * din;
    for (int i = threadIdx.x; i < n; i += blockDim.x) {
        int col = i / din, k = i - col * din;
        dstp[i] = __float2half(W[k * 64 + col]);
    }
}

// ---------------- x -> fp16 ----------------

__global__ void k_xhalf(const float* __restrict__ x, __half* __restrict__ xh, int n4) {
    int i = blockIdx.x * blockDim.x + threadIdx.x;
    if (i < n4) {
        float4 v = ((const float4*)x)[i];
        union { uint2 u; __half2 h2[2]; } pk;
        pk.h2[0] = __floats2half2_rn(v.x, v.y);
        pk.h2[1] = __floats2half2_rn(v.z, v.w);
        ((uint2*)xh)[i] = pk.u;
    }
}

// ---------------- MFMA GEMM: h' = (in @ W) * dinv, fp16 in/out ------------
// Wave = 16 nodes x 64 cols via 4x mfma_f32_16x16x32_f16 per K-chunk.
// A frag: in[node0+(lane&15)][kc*32 + (lane>>4)*8 ..+8]  (16B load)
// B frag: Wt[(ct*16+lane&15)][kc*32 + (lane>>4)*8 ..+8]  (16B load, L1-hot)
// D: row=(lane>>4)*4+reg, col=lane&15 (m89-verified). No LDS.

template<int DIN>
__global__ __launch_bounds__(256) void k_gemm(const __half* __restrict__ in,
                                              const __half* __restrict__ Wt,
                                              const float* __restrict__ dinv,
                                              __half* __restrict__ h) {
    int tid  = threadIdx.x;
    int lane = tid & 63;
    int node0 = blockIdx.x * 64 + (tid >> 6) * 16;
    if (node0 >= N_NODES) return;
    int lr = lane & 15;
    int lk = (lane >> 4) * 8;

    int arow = node0 + lr; if (arow >= N_NODES) arow = N_NODES - 1;
    const __half* ap = in + (size_t)arow * DIN + lk;
    const __half* bp = Wt + (size_t)lr * DIN + lk;

    floatx4 acc0 = {0.f, 0.f, 0.f, 0.f}, acc1 = acc0, acc2 = acc0, acc3 = acc0;
#pragma unroll
    for (int kc = 0; kc < DIN / 32; ++kc) {
        half8_t a  = *(const half8_t*)(ap + kc * 32);
        half8_t b0 = *(const half8_t*)(bp + kc * 32);
        half8_t b1 = *(const half8_t*)(bp + kc * 32 + 16 * DIN);
        half8_t b2 = *(const half8_t*)(bp + kc * 32 + 32 * DIN);
        half8_t b3 = *(const half8_t*)(bp + kc * 32 + 48 * DIN);
        acc0 = __builtin_amdgcn_mfma_f32_16x16x32_f16(a, b0, acc0, 0, 0, 0);
        acc1 = __builtin_amdgcn_mfma_f32_16x16x32_f16(a, b1, acc1, 0, 0, 0);
        acc2 = __builtin_amdgcn_mfma_f32_16x16x32_f16(a, b2, acc2, 0, 0, 0);
        acc3 = __builtin_amdgcn_mfma_f32_16x16x32_f16(a, b3, acc3, 0, 0, 0);
    }

    int rbase = node0 + (lane >> 4) * 4;
#pragma unroll
    for (int r = 0; r < 4; ++r) {
        int row = rbase + r;
        if (row < N_NODES) {
            float dn = dinv[row];
            __half* op = h + ((size_t)row << 6) + lr;
            op[0]  = __float2half(acc0[r] * dn);
            op[16] = __float2half(acc1[r] * dn);
            op[32] = __float2half(acc2[r] * dn);
            op[48] = __float2half(acc3[r] * dn);
        }
    }
}

// ---------------- fused aggregate (fp16 gather, packed fp16 accumulate) ---

template<int LAST>
__global__ __launch_bounds__(256) void k_aggregate(const int* __restrict__ rowptr,
                                                   const int* __restrict__ colv,
                                                   const __half* __restrict__ h,
                                                   const float* __restrict__ dinv,
                                                   const float* __restrict__ bias,
                                                   __half* __restrict__ acta,
                                                   float* __restrict__ outf) {
    int tid  = threadIdx.x;
    int node = blockIdx.x * 16 + (tid >> 4);
    if (node >= N_NODES) return;
    int ql = tid & 15;                          // owns cols ql*4 .. ql*4+3

    int beg = rowptr[node], end = rowptr[node + 1];
    const __half* hp = h + (ql << 2);

    __half2 a0 = __floats2half2_rn(0.f, 0.f), a1 = a0, b0 = a0, b1 = a0;
    int k = beg;
    for (; k + 4 <= end; k += 4) {
        int s0 = colv[k], s1 = colv[k + 1], s2 = colv[k + 2], s3 = colv[k + 3];
        union { uint2 u; __half2 h2[2]; } v0, v1, v2, v3;
        v0.u = *(const uint2*)(hp + ((size_t)s0 << 6));
        v1.u = *(const uint2*)(hp + ((size_t)s1 << 6));
        v2.u = *(const uint2*)(hp + ((size_t)s2 << 6));
        v3.u = *(const uint2*)(hp + ((size_t)s3 << 6));
        a0 = __hadd2(a0, v0.h2[0]); a1 = __hadd2(a1, v0.h2[1]);
        b0 = __hadd2(b0, v1.h2[0]); b1 = __hadd2(b1, v1.h2[1]);
        a0 = __hadd2(a0, v2.h2[0]); a1 = __hadd2(a1, v2.h2[1]);
        b0 = __hadd2(b0, v3.h2[0]); b1 = __hadd2(b1, v3.h2[1]);
    }
    for (; k < end; ++k) {
        int s0 = colv[k];
        union { uint2 u; __half2 h2[2]; } v0;
        v0.u = *(const uint2*)(hp + ((size_t)s0 << 6));
        a0 = __hadd2(a0, v0.h2[0]); a1 = __hadd2(a1, v0.h2[1]);
    }
    a0 = __hadd2(a0, b0); a1 = __hadd2(a1, b1);

    float2 f0 = __half22float2(a0), f1 = __half22float2(a1);
    union { uint2 u; __half2 h2[2]; } sv;
    sv.u = *(const uint2*)(hp + ((size_t)node << 6));
    float2 s0f = __half22float2(sv.h2[0]), s1f = __half22float2(sv.h2[1]);
    float dn = dinv[node];
    float4 bv = ((const float4*)bias)[ql];
    float r0 = fmaxf(fmaf(f0.x + s0f.x, dn, bv.x), 0.f);
    float r1 = fmaxf(fmaf(f0.y + s0f.y, dn, bv.y), 0.f);
    float r2 = fmaxf(fmaf(f1.x + s1f.x, dn, bv.z), 0.f);
    float r3 = fmaxf(fmaf(f1.y + s1f.y, dn, bv.w), 0.f);

    if (LAST) {
        float m = fmaxf(fmaxf(r0, r1), fmaxf(r2, r3));
#pragma unroll
        for (int off = 1; off <= 8; off <<= 1) m = fmaxf(m, __shfl_xor(m, off));
        float ss = expf(r0 - m) + expf(r1 - m) + expf(r2 - m) + expf(r3 - m);
#pragma unroll
        for (int off = 1; off <= 8; off <<= 1) ss += __shfl_xor(ss, off);
        float lse = m + logf(ss);
        *(float4*)(outf + ((size_t)node << 6) + (ql << 2)) =
            make_float4(r0 - lse, r1 - lse, r2 - lse, r3 - lse);
    } else {
        union { uint2 u; __half2 h2[2]; } pk;
        pk.h2[0] = __floats2half2_rn(r0, r1);
        pk.h2[1] = __floats2half2_rn(r2, r3);
        *(uint2*)(acta + ((size_t)node << 6) + (ql << 2)) = pk.u;
    }
}

// ---------------- launch ----------------

extern "C" void kernel_launch(void* const* d_in, const int* in_sizes, int n_in,
                              void* d_out, int out_size, void* d_ws, size_t ws_size,
                              hipStream_t stream) {
    const float* x = (const float*)d_in[0];
    const int* ei  = (const int*)d_in[1];   // harness delivers integers as int32
    const int* src = ei;
    const int* dst = ei + N_EDGES;

    const float* W[6];
    const float* b[6];
    for (int i = 0; i < 6; ++i) {
        W[i] = (const float*)d_in[2 + 2 * i];
        b[i] = (const float*)d_in[3 + 2 * i];
    }
    float* out = (float*)d_out;

    // workspace: h | act | xh | wt | rowptr | dinv | colv
    // build-only arrays alias the h region (dead until first GEMM).
    char* p = (char*)d_ws;
    __half* h      = (__half*)p; p += (size_t)N_NODES * 64 * 2;    // 12.8 MB
    __half* act    = (__half*)p; p += (size_t)N_NODES * 64 * 2;    // 12.8 MB
    __half* xh     = (__half*)p; p += (size_t)N_NODES * 128 * 2;   // 25.6 MB
    __half* wt     = (__half*)p; p += 28672 * 2;                   // 56 KB
    int*    rowptr = (int*)p;    p += (size_t)(N_NODES + 1) * 4;
    float*  dinv   = (float*)p;  p += (size_t)N_NODES * 4;
    int*    colv   = (int*)p;
    unsigned* bentry = (unsigned*)h;                       // 6.4 MB (aliases h)
    int*    ghist = (int*)(bentry + (size_t)N_EDGES);      // NB*128 ints (800 KB)
    int*    btot  = ghist + (size_t)NB * NBLK_S;
    int*    bbase = btot + NB;

    const int nb_q    = (N_NODES + 15) / 16;    // aggregate: 1 node/quarter-wave
    const int nb_tile = (N_NODES + 63) / 64;    // gemm: 64 nodes/block
    const int n4      = N_NODES * 128 / 4;

    // prep (independent of build)
    k_prepw<<<6, 256, 0, stream>>>(W[0], W[1], W[2], W[3], W[4], W[5], wt);
    k_xhalf<<<(n4 + 255) / 256, 256, 0, stream>>>(x, xh, n4);

    // CSR build: counting sort by bucket, then in-bucket refine.
    k_hist<<<NBLK_S, 256, 0, stream>>>(dst, ghist);
    k_scanb<<<NB, NBLK_S, 0, stream>>>(ghist, btot);
    k_scant<<<1, 1024, 0, stream>>>(btot, bbase, rowptr);
    k_scatter<<<NBLK_S, 256, 0, stream>>>(src, dst, ghist, bbase, bentry);
    k_fill2<<<NB, 256, 0, stream>>>(btot, bbase, bentry, rowptr, dinv, colv);

    // 6 GCN layers; gemm(in -> h), aggregate(h -> act / d_out)
    for (int l = 0; l < 6; ++l) {
        if (l == 0)
            k_gemm<128><<<nb_tile, 256, 0, stream>>>(xh, wt, dinv, h);
        else
            k_gemm<64><<<nb_tile, 256, 0, stream>>>(act, wt + 8192 + (l - 1) * 4096, dinv, h);
        if (l == 5)
            k_aggregate<1><<<nb_q, 256, 0, stream>>>(rowptr, colv, h, dinv, b[l], act, out);
        else
            k_aggregate<0><<<nb_q, 256, 0, stream>>>(rowptr, colv, h, dinv, b[l], act, out);
    }
}

// Round 12
// 351.538 us; speedup vs baseline: 2.4792x; 1.0863x over previous
//
#include <hip/hip_runtime.h>
#include <hip/hip_fp16.h>
#include <math.h>

#define N_NODES 100000
#define N_EDGES 1600000
#define NB 1563          // ceil(N_NODES / 64) buckets, bucket = dst >> 6
#define CAP 2048         // LDS staging per bucket in k_fill2 (mean 1024, sd ~32)
#define NBLK_S 128       // scatter/hist blocks
#define CHUNK (N_EDGES / NBLK_S)   // 12500 edges per block (divides exactly)

typedef _Float16 half8_t __attribute__((ext_vector_type(8)));
typedef float floatx4 __attribute__((ext_vector_type(4)));

// ---------------- counting-sort CSR build ----------------

// Pass 1: per-block histogram over buckets (LDS), int4-unrolled, 16 waves.
__global__ __launch_bounds__(1024) void k_hist(const int* __restrict__ dst,
                                               int* __restrict__ ghist) {
    __shared__ int hist[NB];
    int blk = blockIdx.x, t = threadIdx.x;
    for (int i = t; i < NB; i += 1024) hist[i] = 0;
    __syncthreads();
    const int4* dq = (const int4*)(dst + blk * CHUNK);
    const int nq = CHUNK >> 2;                 // 3125 quads
    for (int i = t; i < nq; i += 1024) {
        int4 d = dq[i];
        atomicAdd(&hist[d.x >> 6], 1);
        atomicAdd(&hist[d.y >> 6], 1);
        atomicAdd(&hist[d.z >> 6], 1);
        atomicAdd(&hist[d.w >> 6], 1);
    }
    __syncthreads();
    for (int i = t; i < NB; i += 1024) ghist[i * NBLK_S + blk] = hist[i];
}

// Pass 2: exclusive scan of the 128 block-counts within each bucket.
__global__ void k_scanb(int* __restrict__ ghist, int* __restrict__ btot) {
    __shared__ int s[NBLK_S];
    int b = blockIdx.x, t = threadIdx.x;
    int v = ghist[b * NBLK_S + t];
    s[t] = v;
    __syncthreads();
    for (int off = 1; off < NBLK_S; off <<= 1) {
        int a = (t >= off) ? s[t - off] : 0;
        __syncthreads();
        s[t] += a;
        __syncthreads();
    }
    ghist[b * NBLK_S + t] = s[t] - v;
    if (t == NBLK_S - 1) btot[b] = s[t];
}

// Pass 3: exclusive scan of the 1563 bucket totals (single block, 2 chunks).
__global__ void k_scant(const int* __restrict__ btot, int* __restrict__ bbase,
                        int* __restrict__ rowptr) {
    __shared__ int s[1024];
    __shared__ int carry;
    int t = threadIdx.x;
    if (t == 0) carry = 0;
    __syncthreads();
    for (int chunk = 0; chunk < 2; ++chunk) {
        int i = chunk * 1024 + t;
        int v = (i < NB) ? btot[i] : 0;
        s[t] = v;
        __syncthreads();
        for (int off = 1; off < 1024; off <<= 1) {
            int a = (t >= off) ? s[t - off] : 0;
            __syncthreads();
            s[t] += a;
            __syncthreads();
        }
        if (i < NB) bbase[i] = carry + s[t] - v;
        int total = carry + s[1023];
        __syncthreads();
        if (t == 0) carry = total;
        __syncthreads();
    }
    if (t == 0) rowptr[N_NODES] = N_EDGES;
}

// Pass 4: scatter into bucket-sorted bentry, int4-unrolled, 16 waves/block.
// Each (block,bucket) region is exclusively owned by one block.
__global__ __launch_bounds__(1024) void k_scatter(const int* __restrict__ src,
                                                  const int* __restrict__ dst,
                                                  const int* __restrict__ ghist,
                                                  const int* __restrict__ bbase,
                                                  unsigned* __restrict__ bentry) {
    __shared__ int cursor[NB];
    int blk = blockIdx.x, t = threadIdx.x;
    for (int i = t; i < NB; i += 1024)
        cursor[i] = bbase[i] + ghist[i * NBLK_S + blk];
    __syncthreads();
    const int4* dq = (const int4*)(dst + blk * CHUNK);
    const int4* sq = (const int4*)(src + blk * CHUNK);
    const int nq = CHUNK >> 2;
    for (int i = t; i < nq; i += 1024) {
        int4 d = dq[i];
        int4 s = sq[i];
        int p0 = atomicAdd(&cursor[d.x >> 6], 1);
        int p1 = atomicAdd(&cursor[d.y >> 6], 1);
        int p2 = atomicAdd(&cursor[d.z >> 6], 1);
        int p3 = atomicAdd(&cursor[d.w >> 6], 1);
        bentry[p0] = ((unsigned)(d.x & 63) << 17) | (unsigned)s.x;
        bentry[p1] = ((unsigned)(d.y & 63) << 17) | (unsigned)s.y;
        bentry[p2] = ((unsigned)(d.z & 63) << 17) | (unsigned)s.z;
        bentry[p3] = ((unsigned)(d.w & 63) << 17) | (unsigned)s.w;
    }
}

// Pass 5: one block per bucket; LDS histogram -> rowptr/dinv, LDS cursors ->
// colv scatter confined to the bucket's contiguous window.
__global__ __launch_bounds__(256) void k_fill2(const int* __restrict__ btot,
                                               const int* __restrict__ bbase,
                                               const unsigned* __restrict__ bentry,
                                               int* __restrict__ rowptr,
                                               float* __restrict__ dinv,
                                               int* __restrict__ colv) {
    __shared__ unsigned ent[CAP];
    __shared__ int hist[64];
    __shared__ int cursor[64];
    int b = blockIdx.x;
    int t = threadIdx.x;
    int cnt = btot[b]; if (cnt > CAP) cnt = CAP;
    int base = bbase[b];
    if (t < 64) hist[t] = 0;
    __syncthreads();
    const unsigned* be = bentry + base;
    for (int i = t; i < cnt; i += 256) {
        unsigned e = be[i];
        ent[i] = e;
        atomicAdd(&hist[e >> 17], 1);
    }
    __syncthreads();
    if (t < 64) {
        int v = hist[t];
        int incl = v;
#pragma unroll
        for (int off = 1; off < 64; off <<= 1) {
            int a = __shfl_up(incl, off);
            if (t >= off) incl += a;
        }
        int excl = incl - v;
        cursor[t] = excl;
        int node = (b << 6) + t;
        if (node < N_NODES) {
            rowptr[node] = base + excl;
            dinv[node] = rsqrtf((float)(v + 1));   // +1 self-loop
        }
    }
    __syncthreads();
    for (int i = t; i < cnt; i += 256) {
        unsigned e = ent[i];
        int pos = base + atomicAdd(&cursor[e >> 17], 1);
        colv[pos] = (int)(e & 0x1FFFF);
    }
}

// ---------------- weight prep: Wt[l][col][k] = (fp16) W[l][k][col] ---------

__global__ void k_prepw(const float* __restrict__ W1, const float* __restrict__ W2,
                        const float* __restrict__ W3, const float* __restrict__ W4,
                        const float* __restrict__ W5, const float* __restrict__ W6,
                        __half* __restrict__ wt) {
    int l = blockIdx.x;
    const float* W = (l == 0) ? W1 : (l == 1) ? W2 : (l == 2) ? W3
                   : (l == 3) ? W4 : (l == 4) ? W5 : W6;
    int din = (l == 0) ? 128 : 64;
    __half* dstp = wt + ((l == 0) ? 0 : 8192 + (l - 1) * 4096);
    int n = 64 * din;
    for (int i = threadIdx.x; i < n; i += blockDim.x) {
        int col = i / din, k = i - col * din;
        dstp[i] = __float2half(W[k * 64 + col]);
    }
}

// ---------------- MFMA GEMM: h' = (in @ W) * dinv, fp16 out ---------------
// Wave = 16 nodes x 64 cols via 4x mfma_f32_16x16x32_f16 per K-chunk.
// F32IN=1 (layer 0): read fp32 x, convert to half8 in-register (no xhalf pass).
// D: row=(lane>>4)*4+reg, col=lane&15 (m89-verified). No LDS.

template<int DIN, int F32IN>
__global__ __launch_bounds__(256) void k_gemm(const void* __restrict__ in,
                                              const __half* __restrict__ Wt,
                                              const float* __restrict__ dinv,
                                              __half* __restrict__ h) {
    int tid  = threadIdx.x;
    int lane = tid & 63;
    int node0 = blockIdx.x * 64 + (tid >> 6) * 16;
    if (node0 >= N_NODES) return;
    int lr = lane & 15;
    int lk = (lane >> 4) * 8;

    int arow = node0 + lr; if (arow >= N_NODES) arow = N_NODES - 1;
    const __half* ap  = (const __half*)in + (size_t)arow * DIN + lk;
    const float*  ap32 = (const float*)in + (size_t)arow * DIN + lk;
    const __half* bp = Wt + (size_t)lr * DIN + lk;

    floatx4 acc0 = {0.f, 0.f, 0.f, 0.f}, acc1 = acc0, acc2 = acc0, acc3 = acc0;
#pragma unroll
    for (int kc = 0; kc < DIN / 32; ++kc) {
        half8_t a;
        if (F32IN) {
            float4 f0 = *(const float4*)(ap32 + kc * 32);
            float4 f1 = *(const float4*)(ap32 + kc * 32 + 4);
            a[0] = (_Float16)f0.x; a[1] = (_Float16)f0.y;
            a[2] = (_Float16)f0.z; a[3] = (_Float16)f0.w;
            a[4] = (_Float16)f1.x; a[5] = (_Float16)f1.y;
            a[6] = (_Float16)f1.z; a[7] = (_Float16)f1.w;
        } else {
            a = *(const half8_t*)(ap + kc * 32);
        }
        half8_t b0 = *(const half8_t*)(bp + kc * 32);
        half8_t b1 = *(const half8_t*)(bp + kc * 32 + 16 * DIN);
        half8_t b2 = *(const half8_t*)(bp + kc * 32 + 32 * DIN);
        half8_t b3 = *(const half8_t*)(bp + kc * 32 + 48 * DIN);
        acc0 = __builtin_amdgcn_mfma_f32_16x16x32_f16(a, b0, acc0, 0, 0, 0);
        acc1 = __builtin_amdgcn_mfma_f32_16x16x32_f16(a, b1, acc1, 0, 0, 0);
        acc2 = __builtin_amdgcn_mfma_f32_16x16x32_f16(a, b2, acc2, 0, 0, 0);
        acc3 = __builtin_amdgcn_mfma_f32_16x16x32_f16(a, b3, acc3, 0, 0, 0);
    }

    int rbase = node0 + (lane >> 4) * 4;
#pragma unroll
    for (int r = 0; r < 4; ++r) {
        int row = rbase + r;
        if (row < N_NODES) {
            float dn = dinv[row];
            __half* op = h + ((size_t)row << 6) + lr;
            op[0]  = __float2half(acc0[r] * dn);
            op[16] = __float2half(acc1[r] * dn);
            op[32] = __float2half(acc2[r] * dn);
            op[48] = __float2half(acc3[r] * dn);
        }
    }
}

// ---------------- fused aggregate (fp16 gather, packed fp16 accumulate) ---
// Quarter-wave (16 lanes) per node; lane owns 4 columns (8B of each 128B
// row). Serial edge loop, unroll x8 (8 independent gathers in flight),
// v_pk_add_f16 into 4 named accumulator pairs, fp32 epilogue.

template<int LAST>
__global__ __launch_bounds__(256) void k_aggregate(const int* __restrict__ rowptr,
                                                   const int* __restrict__ colv,
                                                   const __half* __restrict__ h,
                                                   const float* __restrict__ dinv,
                                                   const float* __restrict__ bias,
                                                   __half* __restrict__ acta,
                                                   float* __restrict__ outf) {
    int tid  = threadIdx.x;
    int node = blockIdx.x * 16 + (tid >> 4);
    if (node >= N_NODES) return;
    int ql = tid & 15;                          // owns cols ql*4 .. ql*4+3

    int beg = rowptr[node], end = rowptr[node + 1];
    const __half* hp = h + (ql << 2);

    __half2 z = __floats2half2_rn(0.f, 0.f);
    __half2 A0 = z, A1 = z, B0 = z, B1 = z, C0 = z, C1 = z, D0 = z, D1 = z;
    union UV { uint2 u; __half2 h2[2]; };
    int k = beg;
    for (; k + 8 <= end; k += 8) {
        int s0 = colv[k],     s1 = colv[k + 1], s2 = colv[k + 2], s3 = colv[k + 3];
        int s4 = colv[k + 4], s5 = colv[k + 5], s6 = colv[k + 6], s7 = colv[k + 7];
        UV v0, v1, v2, v3, v4, v5, v6, v7;
        v0.u = *(const uint2*)(hp + ((size_t)s0 << 6));
        v1.u = *(const uint2*)(hp + ((size_t)s1 << 6));
        v2.u = *(const uint2*)(hp + ((size_t)s2 << 6));
        v3.u = *(const uint2*)(hp + ((size_t)s3 << 6));
        v4.u = *(const uint2*)(hp + ((size_t)s4 << 6));
        v5.u = *(const uint2*)(hp + ((size_t)s5 << 6));
        v6.u = *(const uint2*)(hp + ((size_t)s6 << 6));
        v7.u = *(const uint2*)(hp + ((size_t)s7 << 6));
        A0 = __hadd2(A0, v0.h2[0]); A1 = __hadd2(A1, v0.h2[1]);
        B0 = __hadd2(B0, v1.h2[0]); B1 = __hadd2(B1, v1.h2[1]);
        C0 = __hadd2(C0, v2.h2[0]); C1 = __hadd2(C1, v2.h2[1]);
        D0 = __hadd2(D0, v3.h2[0]); D1 = __hadd2(D1, v3.h2[1]);
        A0 = __hadd2(A0, v4.h2[0]); A1 = __hadd2(A1, v4.h2[1]);
        B0 = __hadd2(B0, v5.h2[0]); B1 = __hadd2(B1, v5.h2[1]);
        C0 = __hadd2(C0, v6.h2[0]); C1 = __hadd2(C1, v6.h2[1]);
        D0 = __hadd2(D0, v7.h2[0]); D1 = __hadd2(D1, v7.h2[1]);
    }
    for (; k + 4 <= end; k += 4) {
        int s0 = colv[k], s1 = colv[k + 1], s2 = colv[k + 2], s3 = colv[k + 3];
        UV v0, v1, v2, v3;
        v0.u = *(const uint2*)(hp + ((size_t)s0 << 6));
        v1.u = *(const uint2*)(hp + ((size_t)s1 << 6));
        v2.u = *(const uint2*)(hp + ((size_t)s2 << 6));
        v3.u = *(const uint2*)(hp + ((size_t)s3 << 6));
        A0 = __hadd2(A0, v0.h2[0]); A1 = __hadd2(A1, v0.h2[1]);
        B0 = __hadd2(B0, v1.h2[0]); B1 = __hadd2(B1, v1.h2[1]);
        C0 = __hadd2(C0, v2.h2[0]); C1 = __hadd2(C1, v2.h2[1]);
        D0 = __hadd2(D0, v3.h2[0]); D1 = __hadd2(D1, v3.h2[1]);
    }
    for (; k < end; ++k) {
        int s0 = colv[k];
        UV v0;
        v0.u = *(const uint2*)(hp + ((size_t)s0 << 6));
        A0 = __hadd2(A0, v0.h2[0]); A1 = __hadd2(A1, v0.h2[1]);
    }
    A0 = __hadd2(__hadd2(A0, B0), __hadd2(C0, D0));
    A1 = __hadd2(__hadd2(A1, B1), __hadd2(C1, D1));

    // fp32 epilogue: self-loop + normalize + bias + relu
    float2 f0 = __half22float2(A0), f1 = __half22float2(A1);
    UV sv;
    sv.u = *(const uint2*)(hp + ((size_t)node << 6));
    float2 s0f = __half22float2(sv.h2[0]), s1f = __half22float2(sv.h2[1]);
    float dn = dinv[node];
    float4 bv = ((const float4*)bias)[ql];
    float r0 = fmaxf(fmaf(f0.x + s0f.x, dn, bv.x), 0.f);
    float r1 = fmaxf(fmaf(f0.y + s0f.y, dn, bv.y), 0.f);
    float r2 = fmaxf(fmaf(f1.x + s1f.x, dn, bv.z), 0.f);
    float r3 = fmaxf(fmaf(f1.y + s1f.y, dn, bv.w), 0.f);

    if (LAST) {
        float m = fmaxf(fmaxf(r0, r1), fmaxf(r2, r3));
#pragma unroll
        for (int off = 1; off <= 8; off <<= 1) m = fmaxf(m, __shfl_xor(m, off));
        float ss = expf(r0 - m) + expf(r1 - m) + expf(r2 - m) + expf(r3 - m);
#pragma unroll
        for (int off = 1; off <= 8; off <<= 1) ss += __shfl_xor(ss, off);
        float lse = m + logf(ss);
        *(float4*)(outf + ((size_t)node << 6) + (ql << 2)) =
            make_float4(r0 - lse, r1 - lse, r2 - lse, r3 - lse);
    } else {
        UV pk;
        pk.h2[0] = __floats2half2_rn(r0, r1);
        pk.h2[1] = __floats2half2_rn(r2, r3);
        *(uint2*)(acta + ((size_t)node << 6) + (ql << 2)) = pk.u;
    }
}

// ---------------- launch ----------------

extern "C" void kernel_launch(void* const* d_in, const int* in_sizes, int n_in,
                              void* d_out, int out_size, void* d_ws, size_t ws_size,
                              hipStream_t stream) {
    const float* x = (const float*)d_in[0];
    const int* ei  = (const int*)d_in[1];   // harness delivers integers as int32
    const int* src = ei;
    const int* dst = ei + N_EDGES;

    const float* W[6];
    const float* b[6];
    for (int i = 0; i < 6; ++i) {
        W[i] = (const float*)d_in[2 + 2 * i];
        b[i] = (const float*)d_in[3 + 2 * i];
    }
    float* out = (float*)d_out;

    // workspace: h | act | wt | rowptr | dinv | colv
    // build-only arrays alias the h region (dead until first GEMM).
    char* p = (char*)d_ws;
    __half* h      = (__half*)p; p += (size_t)N_NODES * 64 * 2;    // 12.8 MB
    __half* act    = (__half*)p; p += (size_t)N_NODES * 64 * 2;    // 12.8 MB
    __half* wt     = (__half*)p; p += 28672 * 2;                   // 56 KB
    int*    rowptr = (int*)p;    p += (size_t)(N_NODES + 1) * 4;
    float*  dinv   = (float*)p;  p += (size_t)N_NODES * 4;
    int*    colv   = (int*)p;
    unsigned* bentry = (unsigned*)h;                       // 6.4 MB (aliases h)
    int*    ghist = (int*)(bentry + (size_t)N_EDGES);      // NB*128 ints (800 KB)
    int*    btot  = ghist + (size_t)NB * NBLK_S;
    int*    bbase = btot + NB;

    const int nb_q    = (N_NODES + 15) / 16;    // aggregate: 1 node/quarter-wave
    const int nb_tile = (N_NODES + 63) / 64;    // gemm: 64 nodes/block

    // weight prep (independent of build)
    k_prepw<<<6, 256, 0, stream>>>(W[0], W[1], W[2], W[3], W[4], W[5], wt);

    // CSR build: counting sort by bucket, then in-bucket refine.
    k_hist<<<NBLK_S, 1024, 0, stream>>>(dst, ghist);
    k_scanb<<<NB, NBLK_S, 0, stream>>>(ghist, btot);
    k_scant<<<1, 1024, 0, stream>>>(btot, bbase, rowptr);
    k_scatter<<<NBLK_S, 1024, 0, stream>>>(src, dst, ghist, bbase, bentry);
    k_fill2<<<NB, 256, 0, stream>>>(btot, bbase, bentry, rowptr, dinv, colv);

    // 6 GCN layers; gemm(in -> h), aggregate(h -> act / d_out)
    for (int l = 0; l < 6; ++l) {
        if (l == 0)
            k_gemm<128, 1><<<nb_tile, 256, 0, stream>>>(x, wt, dinv, h);
        else
            k_gemm<64, 0><<<nb_tile, 256, 0, stream>>>(act, wt + 8192 + (l - 1) * 4096, dinv, h);
        if (l == 5)
            k_aggregate<1><<<nb_q, 256, 0, stream>>>(rowptr, colv, h, dinv, b[l], act, out);
        else
            k_aggregate<0><<<nb_q, 256, 0, stream>>>(rowptr, colv, h, dinv, b[l], act, out);
    }
}